// Round 3
// baseline (88.238 us; speedup 1.0000x reference)
//
#include <hip/hip_runtime.h>
#include <hip/hip_bf16.h>
#include <cstdint>
#include <cstddef>

#define NB 4096     // batch rows
#define NC 1000     // real classes
#define NCP 1024    // padded classes
#define ND 3072     // feature dim

typedef __attribute__((ext_vector_type(8))) __bf16 bf16x8;
typedef __attribute__((ext_vector_type(4))) float f32x4;
typedef __attribute__((ext_vector_type(4))) unsigned short u16x4;
typedef unsigned short u16;

__device__ __forceinline__ u16 f2bf_rne(float x) {
    uint32_t u = __float_as_uint(x);
    uint32_t r = (u + 0x7fffu + ((u >> 16) & 1u)) >> 16;
    return (u16)r;
}

// ---------------------------------------------------------------------------
// Convert f32 rows -> bf16 rows, computing per-row sum of squares (in f32).
// Rows >= nrows_src are zero-padded with sq = pad_sq (kills padded classes in
// the logsumexp: dists_pad = -0.5*(z2 + 1e30) -> exp -> 0).
// ---------------------------------------------------------------------------
__global__ __launch_bounds__(256) void convert_rows_kernel(
        const float* __restrict__ src, u16* __restrict__ dst,
        float* __restrict__ sq, int nrows_src, float pad_sq) {
    const int row = blockIdx.x;
    const int tid = threadIdx.x;
    u16* drow = dst + (size_t)row * ND;
    if (row < nrows_src) {
        const float4* s = (const float4*)(src + (size_t)row * ND);
        float acc = 0.f;
#pragma unroll
        for (int i = 0; i < 3; ++i) {                // 768 float4 / 256 threads
            const int idx = tid + i * 256;
            float4 v = s[idx];
            acc = fmaf(v.x, v.x, acc);
            acc = fmaf(v.y, v.y, acc);
            acc = fmaf(v.z, v.z, acc);
            acc = fmaf(v.w, v.w, acc);
            u16x4 o;
            o.x = f2bf_rne(v.x); o.y = f2bf_rne(v.y);
            o.z = f2bf_rne(v.z); o.w = f2bf_rne(v.w);
            *(u16x4*)(drow + idx * 4) = o;
        }
#pragma unroll
        for (int off = 32; off > 0; off >>= 1) acc += __shfl_xor(acc, off, 64);
        __shared__ float ssum[4];
        const int wid = tid >> 6, lane = tid & 63;
        if (lane == 0) ssum[wid] = acc;
        __syncthreads();
        if (tid == 0) sq[row] = ssum[0] + ssum[1] + ssum[2] + ssum[3];
    } else {
        u16x4 z4 = (u16x4){0, 0, 0, 0};
#pragma unroll
        for (int i = 0; i < 3; ++i) *(u16x4*)(drow + (tid + i * 256) * 4) = z4;
        if (tid == 0) sq[row] = pad_sq;
    }
}

// ---------------------------------------------------------------------------
// dists[b][c] = z_b . mu_c - 0.5*(||z_b||^2 + ||mu_c||^2)
// BM=128 x BN=128, BK=64, 256 threads (4 waves, 2x2, wave tile 64x64, 4x4 acc).
// 2-phase double-buffered LDS (T3-minimum): stage(next) -> compute(cur) ->
// one __syncthreads per K-step. T2 XOR-swizzle via pre-swizzled global source.
// ---------------------------------------------------------------------------
#define BM 128
#define BN 128
#define BK 64
#define KITERS (ND / BK)        // 48
#define ABUF (BM * BK)          // 8192 elems (16 KiB)
#define BBUF (BN * BK)

#define GLOAD_LDS16(gp, lp)                                            \
    __builtin_amdgcn_global_load_lds(                                  \
        (const __attribute__((address_space(1))) void*)(gp),           \
        (__attribute__((address_space(3))) void*)(lp), 16, 0, 0)

__global__ __launch_bounds__(256) void gemm_dists_kernel(
        const u16* __restrict__ zb, const u16* __restrict__ mb,
        const float* __restrict__ z2, const float* __restrict__ m2,
        float* __restrict__ dists) {
    __shared__ u16 As[2 * ABUF];   // 32 KiB total (2 bufs)
    __shared__ u16 Bs[2 * BBUF];   // 32 KiB

    const int tid  = threadIdx.x;
    const int wid  = tid >> 6;
    const int lane = tid & 63;
    const int wr   = wid >> 1;        // wave row 0..1 (64 rows each)
    const int wc   = wid & 1;         // wave col 0..1 (64 cols each)
    const int lrow = lane & 15;       // fragment row index
    const int kgrp = lane >> 4;       // k-group 0..3

    // T1: bijective XCD-chunked swizzle (nwg = 256, 256 % 8 == 0)
    const int bid = blockIdx.y * gridDim.x + blockIdx.x;
    const int swz = (bid & 7) * 32 + (bid >> 3);
    const int brow = (swz >> 3) * BM;     // gridDim.x = 8
    const int bcol = (swz & 7) * BN;

    f32x4 acc[4][4];
#pragma unroll
    for (int m = 0; m < 4; ++m)
#pragma unroll
        for (int n = 0; n < 4; ++n) acc[m][n] = (f32x4){0.f, 0.f, 0.f, 0.f};

    // Staging: chunk c (16B) -> physical (row = c>>3, slot p = c&7).
    // Physical slot p holds global k-slot s = p ^ (row&7) (XOR involution).
    const u16* gA[4]; const u16* gB[4];
    u16* lA[4];       u16* lB[4];
#pragma unroll
    for (int g = 0; g < 4; ++g) {
        const int c = g * 256 + tid;
        const int r = c >> 3, p = c & 7, s = p ^ (r & 7);
        gA[g] = zb + (size_t)(brow + r) * ND + s * 8;
        gB[g] = mb + (size_t)(bcol + r) * ND + s * 8;
        lA[g] = As + (g * 256 + wid * 64) * 8;   // wave-uniform base
        lB[g] = Bs + (g * 256 + wid * 64) * 8;
    }

    const int lx = lrow & 7;

    // prologue: stage tile 0 into buf 0
#pragma unroll
    for (int g = 0; g < 4; ++g) GLOAD_LDS16(gA[g], lA[g]);
#pragma unroll
    for (int g = 0; g < 4; ++g) GLOAD_LDS16(gB[g], lB[g]);
    __syncthreads();

    for (int t = 0; t < KITERS; ++t) {
        // stage next tile into the other buffer (skipped on last iter)
        if (t + 1 < KITERS) {
            const int nb = (t + 1) & 1;
            const int k0 = (t + 1) * BK;
#pragma unroll
            for (int g = 0; g < 4; ++g) GLOAD_LDS16(gA[g] + k0, lA[g] + nb * ABUF);
#pragma unroll
            for (int g = 0; g < 4; ++g) GLOAD_LDS16(gB[g] + k0, lB[g] + nb * BBUF);
        }
        // compute current buffer
        const int cb = t & 1;
        const u16* Ac = As + cb * ABUF;
        const u16* Bc = Bs + cb * BBUF;
#pragma unroll
        for (int ks = 0; ks < 2; ++ks) {
            const int pk = (ks * 4 + kgrp) ^ lx;
            bf16x8 a[4], b[4];
#pragma unroll
            for (int m = 0; m < 4; ++m)
                a[m] = *(const bf16x8*)&Ac[(wr * 64 + m * 16 + lrow) * BK + pk * 8];
#pragma unroll
            for (int n = 0; n < 4; ++n)
                b[n] = *(const bf16x8*)&Bc[(wc * 64 + n * 16 + lrow) * BK + pk * 8];
#pragma unroll
            for (int m = 0; m < 4; ++m)
#pragma unroll
                for (int n = 0; n < 4; ++n)
                    acc[m][n] = __builtin_amdgcn_mfma_f32_16x16x32_bf16(
                        a[m], b[n], acc[m][n], 0, 0, 0);
        }
        __syncthreads();   // drains vmcnt (next tile staged) + syncs LDS reads
    }

    // epilogue: C/D layout col = lane&15, row = (lane>>4)*4 + r
#pragma unroll
    for (int n = 0; n < 4; ++n) {
        const int gcol = bcol + wc * 64 + n * 16 + lrow;
        const float mhalf = 0.5f * m2[gcol];
#pragma unroll
        for (int m = 0; m < 4; ++m) {
#pragma unroll
            for (int r = 0; r < 4; ++r) {
                const int grow = brow + wr * 64 + m * 16 + kgrp * 4 + r;
                dists[(size_t)grow * NCP + gcol] =
                    acc[m][n][r] - 0.5f * z2[grow] - mhalf;
            }
        }
    }
}

// ---------------------------------------------------------------------------
// Per-row logsumexp + picked: outA[b] = lse - dists[b,label], outB[b] = lse + sldj
// ---------------------------------------------------------------------------
__global__ __launch_bounds__(256) void row_lse_kernel(
        const float* __restrict__ dists, const int* __restrict__ labels,
        const float* __restrict__ sldj, float* __restrict__ outA,
        float* __restrict__ outB) {
    const int row = blockIdx.x;
    const int tid = threadIdx.x;
    const float* dr = dists + (size_t)row * NCP;
    float4 v = ((const float4*)dr)[tid];     // 256 * 4 = 1024 exactly

    float mx = fmaxf(fmaxf(v.x, v.y), fmaxf(v.z, v.w));
#pragma unroll
    for (int off = 32; off > 0; off >>= 1) mx = fmaxf(mx, __shfl_xor(mx, off, 64));
    __shared__ float smax[4], ssum[4];
    const int wid = tid >> 6, lane = tid & 63;
    if (lane == 0) smax[wid] = mx;
    __syncthreads();
    const float bm = fmaxf(fmaxf(smax[0], smax[1]), fmaxf(smax[2], smax[3]));

    float s = expf(v.x - bm) + expf(v.y - bm) + expf(v.z - bm) + expf(v.w - bm);
#pragma unroll
    for (int off = 32; off > 0; off >>= 1) s += __shfl_xor(s, off, 64);
    if (lane == 0) ssum[wid] = s;
    __syncthreads();
    if (tid == 0) {
        const float tot = ssum[0] + ssum[1] + ssum[2] + ssum[3];
        const float lpz = bm + logf(tot);
        const float picked = dr[labels[row]];
        outA[row] = lpz - picked;
        outB[row] = lpz + sldj[row];
    }
}

// ---------------------------------------------------------------------------
// Deterministic final reduction (single block, fixed tree order).
// ---------------------------------------------------------------------------
__global__ __launch_bounds__(1024) void finalize_kernel(
        const float* __restrict__ a, const float* __restrict__ b,
        const float* __restrict__ beta, float* __restrict__ out) {
    __shared__ float sa[1024], sb[1024];
    const int tid = threadIdx.x;
    float va = 0.f, vb = 0.f;
    for (int i = tid; i < NB; i += 1024) { va += a[i]; vb += b[i]; }
    sa[tid] = va; sb[tid] = vb;
    __syncthreads();
    for (int s = 512; s > 0; s >>= 1) {
        if (tid < s) { sa[tid] += sa[tid + s]; sb[tid] += sb[tid + s]; }
        __syncthreads();
    }
    if (tid == 0) {
        const float loss_cls = sa[0] / (float)NB;
        const float loss_gen = -(sb[0] / (float)NB) / (float)ND;
        const float total = loss_gen + beta[0] * loss_cls;
        out[0] = total;
        out[1] = loss_gen;
        out[2] = loss_cls;
    }
}

extern "C" void kernel_launch(void* const* d_in, const int* in_sizes, int n_in,
                              void* d_out, int out_size, void* d_ws, size_t ws_size,
                              hipStream_t stream) {
    const float* z      = (const float*)d_in[0];
    const float* sldj   = (const float*)d_in[1];
    const int*   labels = (const int*)d_in[2];
    const float* beta   = (const float*)d_in[3];
    const float* means  = (const float*)d_in[4];
    float* out = (float*)d_out;

    char* ws = (char*)d_ws;
    size_t off = 0;
    u16* zb = (u16*)(ws + off);      off += (size_t)NB * ND * 2;    // 25.2 MB
    u16* mb = (u16*)(ws + off);      off += (size_t)NCP * ND * 2;   //  6.3 MB
    float* z2 = (float*)(ws + off);  off += (size_t)NB * 4;
    float* m2 = (float*)(ws + off);  off += (size_t)NCP * 4;
    float* dists = (float*)(ws + off); off += (size_t)NB * NCP * 4; // 16.8 MB
    float* ra = (float*)(ws + off);  off += (size_t)NB * 4;
    float* rb = (float*)(ws + off);  off += (size_t)NB * 4;

    convert_rows_kernel<<<NB, 256, 0, stream>>>(z, zb, z2, NB, 0.f);
    convert_rows_kernel<<<NCP, 256, 0, stream>>>(means, mb, m2, NC, 1e30f);
    gemm_dists_kernel<<<dim3(NCP / BN, NB / BM), 256, 0, stream>>>(zb, mb, z2, m2, dists);
    row_lse_kernel<<<NB, 256, 0, stream>>>(dists, labels, sldj, ra, rb);
    finalize_kernel<<<1, 1024, 0, stream>>>(ra, rb, beta, out);
}

// Round 4
// 80.296 us; speedup vs baseline: 1.0989x; 1.0989x over previous
//
#include <hip/hip_runtime.h>
#include <hip/hip_bf16.h>
#include <cstdint>
#include <cstddef>

#define NB 4096     // batch rows
#define NC 1000     // real classes
#define NCP 1024    // padded classes
#define ND 3072     // feature dim

typedef __attribute__((ext_vector_type(8))) __bf16 bf16x8;
typedef __attribute__((ext_vector_type(4))) float f32x4;
typedef __attribute__((ext_vector_type(4))) unsigned short u16x4;
typedef unsigned short u16;

__device__ __forceinline__ u16 f2bf_rne(float x) {
    uint32_t u = __float_as_uint(x);
    uint32_t r = (u + 0x7fffu + ((u >> 16) & 1u)) >> 16;
    return (u16)r;
}

// ---------------------------------------------------------------------------
// Convert f32 rows -> bf16 rows, computing per-row sum of squares (in f32).
// Rows >= nrows_src are zero-padded with sq = pad_sq (kills padded classes in
// the logsumexp: dists_pad = -0.5*(z2 + 1e30) -> exp -> 0).
// ---------------------------------------------------------------------------
__global__ __launch_bounds__(256) void convert_rows_kernel(
        const float* __restrict__ src, u16* __restrict__ dst,
        float* __restrict__ sq, int nrows_src, float pad_sq) {
    const int row = blockIdx.x;
    const int tid = threadIdx.x;
    u16* drow = dst + (size_t)row * ND;
    if (row < nrows_src) {
        const float4* s = (const float4*)(src + (size_t)row * ND);
        float acc = 0.f;
#pragma unroll
        for (int i = 0; i < 3; ++i) {                // 768 float4 / 256 threads
            const int idx = tid + i * 256;
            float4 v = s[idx];
            acc = fmaf(v.x, v.x, acc);
            acc = fmaf(v.y, v.y, acc);
            acc = fmaf(v.z, v.z, acc);
            acc = fmaf(v.w, v.w, acc);
            u16x4 o;
            o.x = f2bf_rne(v.x); o.y = f2bf_rne(v.y);
            o.z = f2bf_rne(v.z); o.w = f2bf_rne(v.w);
            *(u16x4*)(drow + idx * 4) = o;
        }
#pragma unroll
        for (int off = 32; off > 0; off >>= 1) acc += __shfl_xor(acc, off, 64);
        __shared__ float ssum[4];
        const int wid = tid >> 6, lane = tid & 63;
        if (lane == 0) ssum[wid] = acc;
        __syncthreads();
        if (tid == 0) sq[row] = ssum[0] + ssum[1] + ssum[2] + ssum[3];
    } else {
        u16x4 z4 = (u16x4){0, 0, 0, 0};
#pragma unroll
        for (int i = 0; i < 3; ++i) *(u16x4*)(drow + (tid + i * 256) * 4) = z4;
        if (tid == 0) sq[row] = pad_sq;
    }
}

// ---------------------------------------------------------------------------
// cross[b][c] = z_b . mu_c   (raw GEMM; bias fold happens in row_lse)
// BM=128 x BN=128, BK=64, 256 threads (4 waves 2x2, wave tile 64x64, 4x4 acc).
// Depth-3 pipeline: 4 LDS buffers, counted s_waitcnt vmcnt(16) (never drained
// in steady state), ONE raw s_barrier per K-step. T2 XOR-swizzle via
// pre-swizzled global source. No global loads in/around the loop (vmcnt purity).
// ---------------------------------------------------------------------------
#define BM 128
#define BN 128
#define BK 64
#define KITERS (ND / BK)        // 48
#define ABUF (BM * BK)          // 8192 elems (16 KiB)
#define BBUF (BN * BK)

#define GLOAD_LDS16(gp, lp)                                            \
    __builtin_amdgcn_global_load_lds(                                  \
        (const __attribute__((address_space(1))) void*)(gp),           \
        (__attribute__((address_space(3))) void*)(lp), 16, 0, 0)

__global__ __launch_bounds__(256) void gemm_dists_kernel(
        const u16* __restrict__ zb, const u16* __restrict__ mb,
        float* __restrict__ dists) {
    __shared__ u16 As[4 * ABUF];   // 64 KiB (4 buffers)
    __shared__ u16 Bs[4 * BBUF];   // 64 KiB

    const int tid  = threadIdx.x;
    const int wid  = tid >> 6;
    const int lane = tid & 63;
    const int wr   = wid >> 1;        // wave row 0..1 (64 rows each)
    const int wc   = wid & 1;         // wave col 0..1 (64 cols each)
    const int lrow = lane & 15;       // fragment row index
    const int kgrp = lane >> 4;       // k-group 0..3

    // T1: bijective XCD-chunked swizzle (nwg = 256, 256 % 8 == 0)
    const int bid = blockIdx.y * gridDim.x + blockIdx.x;
    const int swz = (bid & 7) * 32 + (bid >> 3);
    const int brow = (swz >> 3) * BM;     // gridDim.x = 8
    const int bcol = (swz & 7) * BN;

    f32x4 acc[4][4];
#pragma unroll
    for (int m = 0; m < 4; ++m)
#pragma unroll
        for (int n = 0; n < 4; ++n) acc[m][n] = (f32x4){0.f, 0.f, 0.f, 0.f};

    // Staging: chunk c (16B) -> physical (row = c>>3, slot p = c&7).
    // Physical slot p holds global k-slot s = p ^ (row&7) (XOR involution).
    const u16* gA[4]; const u16* gB[4];
    u16* lA[4];       u16* lB[4];
#pragma unroll
    for (int g = 0; g < 4; ++g) {
        const int c = g * 256 + tid;
        const int r = c >> 3, p = c & 7, s = p ^ (r & 7);
        gA[g] = zb + (size_t)(brow + r) * ND + s * 8;
        gB[g] = mb + (size_t)(bcol + r) * ND + s * 8;
        lA[g] = As + (g * 256 + wid * 64) * 8;   // wave-uniform base (buf 0)
        lB[g] = Bs + (g * 256 + wid * 64) * 8;
    }

    const int lx = lrow & 7;

    // prologue: stage tiles 0,1,2 into buffers 0,1,2 (24 loads outstanding)
#pragma unroll
    for (int tt = 0; tt < 3; ++tt) {
#pragma unroll
        for (int g = 0; g < 4; ++g) GLOAD_LDS16(gA[g] + tt * BK, lA[g] + tt * ABUF);
#pragma unroll
        for (int g = 0; g < 4; ++g) GLOAD_LDS16(gB[g] + tt * BK, lB[g] + tt * BBUF);
    }

    for (int t = 0; t < KITERS; ++t) {
        // tile t landed when outstanding <= (tiles after t) * 8
        if (t < KITERS - 2)       asm volatile("s_waitcnt vmcnt(16)" ::: "memory");
        else if (t == KITERS - 2) asm volatile("s_waitcnt vmcnt(8)" ::: "memory");
        else                      asm volatile("s_waitcnt vmcnt(0)" ::: "memory");
        __builtin_amdgcn_s_barrier();         // all waves: tile t visible
        __builtin_amdgcn_sched_barrier(0);    // pin: no ds_read above barrier

        // issue tile t+3 into buffer (t+3)&3 (last read at iter t-1; safe)
        if (t + 3 < KITERS) {
            const int nb = (t + 3) & 3;
            const int k0 = (t + 3) * BK;
#pragma unroll
            for (int g = 0; g < 4; ++g) GLOAD_LDS16(gA[g] + k0, lA[g] + nb * ABUF);
#pragma unroll
            for (int g = 0; g < 4; ++g) GLOAD_LDS16(gB[g] + k0, lB[g] + nb * BBUF);
        }

        // compute current buffer
        const int cb = t & 3;
        const u16* Ac = As + cb * ABUF;
        const u16* Bc = Bs + cb * BBUF;
#pragma unroll
        for (int ks = 0; ks < 2; ++ks) {
            const int pk = (ks * 4 + kgrp) ^ lx;
            bf16x8 a[4], b[4];
#pragma unroll
            for (int m = 0; m < 4; ++m)
                a[m] = *(const bf16x8*)&Ac[(wr * 64 + m * 16 + lrow) * BK + pk * 8];
#pragma unroll
            for (int n = 0; n < 4; ++n)
                b[n] = *(const bf16x8*)&Bc[(wc * 64 + n * 16 + lrow) * BK + pk * 8];
#pragma unroll
            for (int m = 0; m < 4; ++m)
#pragma unroll
                for (int n = 0; n < 4; ++n)
                    acc[m][n] = __builtin_amdgcn_mfma_f32_16x16x32_bf16(
                        a[m], b[n], acc[m][n], 0, 0, 0);
        }
        // no drain here: next iter's counted vmcnt + barrier handles readiness;
        // this wave's ds_reads completed before its MFMAs issued (lgkmcnt deps).
    }

    // epilogue: C/D layout col = lane&15, row = (lane>>4)*4 + r  (raw cross)
#pragma unroll
    for (int n = 0; n < 4; ++n) {
        const int gcol = bcol + wc * 64 + n * 16 + lrow;
#pragma unroll
        for (int m = 0; m < 4; ++m) {
#pragma unroll
            for (int r = 0; r < 4; ++r) {
                const int grow = brow + wr * 64 + m * 16 + kgrp * 4 + r;
                dists[(size_t)grow * NCP + gcol] = acc[m][n][r];
            }
        }
    }
}

// ---------------------------------------------------------------------------
// Per-row: fold bias (-0.5*(z2+m2)) into raw cross, then logsumexp + picked.
// outA[b] = lse - dists[b,label], outB[b] = lse + sldj[b]
// ---------------------------------------------------------------------------
__global__ __launch_bounds__(256) void row_lse_kernel(
        const float* __restrict__ cross, const float* __restrict__ z2,
        const float* __restrict__ m2, const int* __restrict__ labels,
        const float* __restrict__ sldj, float* __restrict__ outA,
        float* __restrict__ outB) {
    const int row = blockIdx.x;
    const int tid = threadIdx.x;
    const float* dr = cross + (size_t)row * NCP;
    const float z2h = 0.5f * z2[row];
    float4 v = ((const float4*)dr)[tid];     // 256 * 4 = 1024 exactly
    float4 mm = ((const float4*)m2)[tid];
    v.x = v.x - z2h - 0.5f * mm.x;
    v.y = v.y - z2h - 0.5f * mm.y;
    v.z = v.z - z2h - 0.5f * mm.z;
    v.w = v.w - z2h - 0.5f * mm.w;

    float mx = fmaxf(fmaxf(v.x, v.y), fmaxf(v.z, v.w));
#pragma unroll
    for (int off = 32; off > 0; off >>= 1) mx = fmaxf(mx, __shfl_xor(mx, off, 64));
    __shared__ float smax[4], ssum[4];
    const int wid = tid >> 6, lane = tid & 63;
    if (lane == 0) smax[wid] = mx;
    __syncthreads();
    const float bm = fmaxf(fmaxf(smax[0], smax[1]), fmaxf(smax[2], smax[3]));

    float s = expf(v.x - bm) + expf(v.y - bm) + expf(v.z - bm) + expf(v.w - bm);
#pragma unroll
    for (int off = 32; off > 0; off >>= 1) s += __shfl_xor(s, off, 64);
    if (lane == 0) ssum[wid] = s;
    __syncthreads();
    if (tid == 0) {
        const float tot = ssum[0] + ssum[1] + ssum[2] + ssum[3];
        const float lpz = bm + logf(tot);
        const int lab = labels[row];
        const float picked = dr[lab] - z2h - 0.5f * m2[lab];
        outA[row] = lpz - picked;
        outB[row] = lpz + sldj[row];
    }
}

// ---------------------------------------------------------------------------
// Deterministic final reduction (single block, fixed tree order).
// ---------------------------------------------------------------------------
__global__ __launch_bounds__(1024) void finalize_kernel(
        const float* __restrict__ a, const float* __restrict__ b,
        const float* __restrict__ beta, float* __restrict__ out) {
    __shared__ float sa[1024], sb[1024];
    const int tid = threadIdx.x;
    float va = 0.f, vb = 0.f;
    for (int i = tid; i < NB; i += 1024) { va += a[i]; vb += b[i]; }
    sa[tid] = va; sb[tid] = vb;
    __syncthreads();
    for (int s = 512; s > 0; s >>= 1) {
        if (tid < s) { sa[tid] += sa[tid + s]; sb[tid] += sb[tid + s]; }
        __syncthreads();
    }
    if (tid == 0) {
        const float loss_cls = sa[0] / (float)NB;
        const float loss_gen = -(sb[0] / (float)NB) / (float)ND;
        const float total = loss_gen + beta[0] * loss_cls;
        out[0] = total;
        out[1] = loss_gen;
        out[2] = loss_cls;
    }
}

extern "C" void kernel_launch(void* const* d_in, const int* in_sizes, int n_in,
                              void* d_out, int out_size, void* d_ws, size_t ws_size,
                              hipStream_t stream) {
    const float* z      = (const float*)d_in[0];
    const float* sldj   = (const float*)d_in[1];
    const int*   labels = (const int*)d_in[2];
    const float* beta   = (const float*)d_in[3];
    const float* means  = (const float*)d_in[4];
    float* out = (float*)d_out;

    char* ws = (char*)d_ws;
    size_t off = 0;
    u16* zb = (u16*)(ws + off);      off += (size_t)NB * ND * 2;    // 25.2 MB
    u16* mb = (u16*)(ws + off);      off += (size_t)NCP * ND * 2;   //  6.3 MB
    float* z2 = (float*)(ws + off);  off += (size_t)NB * 4;
    float* m2 = (float*)(ws + off);  off += (size_t)NCP * 4;
    float* dists = (float*)(ws + off); off += (size_t)NB * NCP * 4; // 16.8 MB
    float* ra = (float*)(ws + off);  off += (size_t)NB * 4;
    float* rb = (float*)(ws + off);  off += (size_t)NB * 4;

    convert_rows_kernel<<<NB, 256, 0, stream>>>(z, zb, z2, NB, 0.f);
    convert_rows_kernel<<<NCP, 256, 0, stream>>>(means, mb, m2, NC, 1e30f);
    gemm_dists_kernel<<<dim3(NCP / BN, NB / BM), 256, 0, stream>>>(zb, mb, dists);
    row_lse_kernel<<<NB, 256, 0, stream>>>(dists, z2, m2, labels, sldj, ra, rb);
    finalize_kernel<<<1, 1024, 0, stream>>>(ra, rb, beta, out);
}

// Round 5
// 68.864 us; speedup vs baseline: 1.2814x; 1.1660x over previous
//
#include <hip/hip_runtime.h>
#include <hip/hip_bf16.h>
#include <cstdint>
#include <cstddef>

#define NB 4096     // batch rows
#define NC 1000     // real classes
#define NCP 1024    // padded classes
#define ND 3072     // feature dim

typedef __attribute__((ext_vector_type(8))) __bf16 bf16x8;
typedef __attribute__((ext_vector_type(4))) float f32x4;
typedef __attribute__((ext_vector_type(4))) unsigned short u16x4;
typedef unsigned short u16;

__device__ __forceinline__ u16 f2bf_rne(float x) {
    uint32_t u = __float_as_uint(x);
    uint32_t r = (u + 0x7fffu + ((u >> 16) & 1u)) >> 16;
    return (u16)r;
}

// ---------------------------------------------------------------------------
// Fused convert: blocks [0,NB) convert z rows; blocks [NB, NB+NCP) convert
// means rows (rows >= NC zero-padded with sq = 1e30 to kill them in the LSE).
// ---------------------------------------------------------------------------
__global__ __launch_bounds__(256) void convert_all_kernel(
        const float* __restrict__ z, const float* __restrict__ means,
        u16* __restrict__ zb, u16* __restrict__ mb,
        float* __restrict__ z2, float* __restrict__ m2) {
    const int bidx = blockIdx.x;
    const int tid = threadIdx.x;
    const float* src;
    u16* dst;
    float* sq;
    bool pad = false;
    if (bidx < NB) {
        src = z + (size_t)bidx * ND;
        dst = zb + (size_t)bidx * ND;
        sq = z2 + bidx;
    } else {
        const int mr = bidx - NB;
        dst = mb + (size_t)mr * ND;
        sq = m2 + mr;
        src = means + (size_t)mr * ND;
        pad = (mr >= NC);
    }
    if (!pad) {
        const float4* s = (const float4*)src;
        float acc = 0.f;
#pragma unroll
        for (int i = 0; i < 3; ++i) {                // 768 float4 / 256 threads
            const int idx = tid + i * 256;
            float4 v = s[idx];
            acc = fmaf(v.x, v.x, acc);
            acc = fmaf(v.y, v.y, acc);
            acc = fmaf(v.z, v.z, acc);
            acc = fmaf(v.w, v.w, acc);
            u16x4 o;
            o.x = f2bf_rne(v.x); o.y = f2bf_rne(v.y);
            o.z = f2bf_rne(v.z); o.w = f2bf_rne(v.w);
            *(u16x4*)(dst + idx * 4) = o;
        }
#pragma unroll
        for (int off = 32; off > 0; off >>= 1) acc += __shfl_xor(acc, off, 64);
        __shared__ float ssum[4];
        const int wid = tid >> 6, lane = tid & 63;
        if (lane == 0) ssum[wid] = acc;
        __syncthreads();
        if (tid == 0) sq[0] = ssum[0] + ssum[1] + ssum[2] + ssum[3];
    } else {
        u16x4 z4 = (u16x4){0, 0, 0, 0};
#pragma unroll
        for (int i = 0; i < 3; ++i) *(u16x4*)(dst + (tid + i * 256) * 4) = z4;
        if (tid == 0) sq[0] = 1e30f;
    }
}

// ---------------------------------------------------------------------------
// cross_part[ksl][b][c] = sum over K-slice of z_b . mu_c  (raw partial GEMM).
// 128x128 tile, BK=32, 4 waves (2x2, wave tile 64x64, 4x4 acc).
// 4 LDS buffers (64 KiB -> 2 blocks/CU with split-K grid of 512), depth-3
// prefetch, counted s_waitcnt vmcnt(8), ONE raw s_barrier per K-step.
// T2 XOR swizzle: physical slot p holds k-slot s = p ^ ((row>>1)&3).
// ---------------------------------------------------------------------------
#define BM 128
#define BN 128
#define BK 32
#define ABUF (BM * BK)          // 4096 elems (8 KiB)
#define BBUF (BN * BK)

#define GLOAD_LDS16(gp, lp)                                            \
    __builtin_amdgcn_global_load_lds(                                  \
        (const __attribute__((address_space(1))) void*)(gp),           \
        (__attribute__((address_space(3))) void*)(lp), 16, 0, 0)

template <int NSL>
__global__ __launch_bounds__(256, 2) void gemm_dists_kernel(
        const u16* __restrict__ zb, const u16* __restrict__ mb,
        float* __restrict__ cross) {
    constexpr int KSL = ND / NSL;        // K elems per slice
    constexpr int NT  = KSL / BK;        // tiles per slice (48 for NSL=2)

    __shared__ u16 As[4 * ABUF];   // 32 KiB (4 buffers)
    __shared__ u16 Bs[4 * BBUF];   // 32 KiB

    const int tid  = threadIdx.x;
    const int wid  = tid >> 6;
    const int lane = tid & 63;
    const int wr   = wid >> 1;        // wave row 0..1 (64 rows each)
    const int wc   = wid & 1;         // wave col 0..1 (64 cols each)
    const int lrow = lane & 15;       // fragment row index
    const int kgrp = lane >> 4;       // k-group 0..3

    // T1: bijective XCD-chunked swizzle within each z-slice (256 % 8 == 0)
    const int bid = blockIdx.y * gridDim.x + blockIdx.x;
    const int swz = (bid & 7) * 32 + (bid >> 3);
    const int brow = (swz >> 3) * BM;     // gridDim.x = 8
    const int bcol = (swz & 7) * BN;
    const int kbase = blockIdx.z * KSL;
    float* outp = cross + (size_t)blockIdx.z * NB * NCP;

    f32x4 acc[4][4];
#pragma unroll
    for (int m = 0; m < 4; ++m)
#pragma unroll
        for (int n = 0; n < 4; ++n) acc[m][n] = (f32x4){0.f, 0.f, 0.f, 0.f};

    // Staging: chunk c (16B) -> physical (row = c>>2, slot p = c&3).
    // Physical slot p holds global k-slot s = p ^ ((row>>1)&3).
    const u16* gA[2]; const u16* gB[2];
    u16* lA[2];       u16* lB[2];
#pragma unroll
    for (int g = 0; g < 2; ++g) {
        const int c = g * 256 + tid;
        const int r = c >> 2, p = c & 3, s = p ^ ((r >> 1) & 3);
        gA[g] = zb + (size_t)(brow + r) * ND + kbase + s * 8;
        gB[g] = mb + (size_t)(bcol + r) * ND + kbase + s * 8;
        lA[g] = As + (g * 256 + wid * 64) * 8;   // wave-uniform base (buf 0)
        lB[g] = Bs + (g * 256 + wid * 64) * 8;
    }

#define STAGE(tt) do {                                                   \
        const int bb_ = (tt) & 3;                                        \
        const int ko_ = (tt) * BK;                                       \
        GLOAD_LDS16(gA[0] + ko_, lA[0] + bb_ * ABUF);                    \
        GLOAD_LDS16(gA[1] + ko_, lA[1] + bb_ * ABUF);                    \
        GLOAD_LDS16(gB[0] + ko_, lB[0] + bb_ * BBUF);                    \
        GLOAD_LDS16(gB[1] + ko_, lB[1] + bb_ * BBUF);                    \
    } while (0)

#define COMP(tt) do {                                                    \
        const int cb_ = (tt) & 3;                                        \
        const u16* Ac = As + cb_ * ABUF;                                 \
        const u16* Bc = Bs + cb_ * BBUF;                                 \
        const int pk = kgrp ^ ((lrow >> 1) & 3);                         \
        bf16x8 a[4], b[4];                                               \
        _Pragma("unroll")                                                \
        for (int m = 0; m < 4; ++m)                                      \
            a[m] = *(const bf16x8*)&Ac[(wr * 64 + m * 16 + lrow) * BK + pk * 8]; \
        _Pragma("unroll")                                                \
        for (int n = 0; n < 4; ++n)                                      \
            b[n] = *(const bf16x8*)&Bc[(wc * 64 + n * 16 + lrow) * BK + pk * 8]; \
        _Pragma("unroll")                                                \
        for (int m = 0; m < 4; ++m)                                      \
            _Pragma("unroll")                                            \
            for (int n = 0; n < 4; ++n)                                  \
                acc[m][n] = __builtin_amdgcn_mfma_f32_16x16x32_bf16(     \
                    a[m], b[n], acc[m][n], 0, 0, 0);                     \
    } while (0)

    // prologue: stage tiles 0,1,2 into buffers 0,1,2 (12 loads/wave in flight)
    STAGE(0); STAGE(1); STAGE(2);

    // main loop: counted vmcnt — tiles t+1, t+2 stay in flight across barrier
    for (int t = 0; t < NT - 2; ++t) {
        asm volatile("s_waitcnt vmcnt(8)" ::: "memory");   // tile t landed
        __builtin_amdgcn_s_barrier();
        __builtin_amdgcn_sched_barrier(0);
        if (t + 3 < NT) STAGE(t + 3);   // buf (t+3)&3 = (t-1)&3, free past barrier
        COMP(t);
    }
    // tail: t = NT-2, NT-1
    asm volatile("s_waitcnt vmcnt(4)" ::: "memory");
    __builtin_amdgcn_s_barrier();
    __builtin_amdgcn_sched_barrier(0);
    COMP(NT - 2);
    asm volatile("s_waitcnt vmcnt(0)" ::: "memory");
    __builtin_amdgcn_s_barrier();
    __builtin_amdgcn_sched_barrier(0);
    COMP(NT - 1);

#undef STAGE
#undef COMP

    // epilogue: C/D layout col = lane&15, row = (lane>>4)*4 + r  (raw cross)
#pragma unroll
    for (int n = 0; n < 4; ++n) {
        const int gcol = bcol + wc * 64 + n * 16 + lrow;
#pragma unroll
        for (int m = 0; m < 4; ++m) {
#pragma unroll
            for (int r = 0; r < 4; ++r) {
                const int grow = brow + wr * 64 + m * 16 + kgrp * 4 + r;
                outp[(size_t)grow * NCP + gcol] = acc[m][n][r];
            }
        }
    }
}

// ---------------------------------------------------------------------------
// Per-row: sum K-slice partials, fold bias (-0.5*(z2+m2)), logsumexp + picked.
// outA[b] = lse - dists[b,label], outB[b] = lse + sldj[b]
// ---------------------------------------------------------------------------
template <int NSL>
__global__ __launch_bounds__(256) void row_lse_kernel(
        const float* __restrict__ cross, const float* __restrict__ z2,
        const float* __restrict__ m2, const int* __restrict__ labels,
        const float* __restrict__ sldj, float* __restrict__ outA,
        float* __restrict__ outB) {
    const int row = blockIdx.x;
    const int tid = threadIdx.x;
    const float* dr0 = cross + (size_t)row * NCP;
    const float* dr1 = cross + (size_t)NB * NCP + (size_t)row * NCP;
    const float z2h = 0.5f * z2[row];
    float4 v = ((const float4*)dr0)[tid];    // 256 * 4 = 1024 exactly
    if (NSL == 2) {
        float4 w = ((const float4*)dr1)[tid];
        v.x += w.x; v.y += w.y; v.z += w.z; v.w += w.w;
    }
    float4 mm = ((const float4*)m2)[tid];
    v.x = v.x - z2h - 0.5f * mm.x;
    v.y = v.y - z2h - 0.5f * mm.y;
    v.z = v.z - z2h - 0.5f * mm.z;
    v.w = v.w - z2h - 0.5f * mm.w;

    float mx = fmaxf(fmaxf(v.x, v.y), fmaxf(v.z, v.w));
#pragma unroll
    for (int off = 32; off > 0; off >>= 1) mx = fmaxf(mx, __shfl_xor(mx, off, 64));
    __shared__ float smax[4], ssum[4];
    const int wid = tid >> 6, lane = tid & 63;
    if (lane == 0) smax[wid] = mx;
    __syncthreads();
    const float bm = fmaxf(fmaxf(smax[0], smax[1]), fmaxf(smax[2], smax[3]));

    float s = expf(v.x - bm) + expf(v.y - bm) + expf(v.z - bm) + expf(v.w - bm);
#pragma unroll
    for (int off = 32; off > 0; off >>= 1) s += __shfl_xor(s, off, 64);
    if (lane == 0) ssum[wid] = s;
    __syncthreads();
    if (tid == 0) {
        const float tot = ssum[0] + ssum[1] + ssum[2] + ssum[3];
        const float lpz = bm + logf(tot);
        const int lab = labels[row];
        float pick = dr0[lab];
        if (NSL == 2) pick += dr1[lab];
        pick = pick - z2h - 0.5f * m2[lab];
        outA[row] = lpz - pick;
        outB[row] = lpz + sldj[row];
    }
}

// ---------------------------------------------------------------------------
// Deterministic final reduction (single block, fixed tree order).
// ---------------------------------------------------------------------------
__global__ __launch_bounds__(1024) void finalize_kernel(
        const float* __restrict__ a, const float* __restrict__ b,
        const float* __restrict__ beta, float* __restrict__ out) {
    __shared__ float sa[1024], sb[1024];
    const int tid = threadIdx.x;
    float va = 0.f, vb = 0.f;
    for (int i = tid; i < NB; i += 1024) { va += a[i]; vb += b[i]; }
    sa[tid] = va; sb[tid] = vb;
    __syncthreads();
    for (int s = 512; s > 0; s >>= 1) {
        if (tid < s) { sa[tid] += sa[tid + s]; sb[tid] += sb[tid + s]; }
        __syncthreads();
    }
    if (tid == 0) {
        const float loss_cls = sa[0] / (float)NB;
        const float loss_gen = -(sb[0] / (float)NB) / (float)ND;
        const float total = loss_gen + beta[0] * loss_cls;
        out[0] = total;
        out[1] = loss_gen;
        out[2] = loss_cls;
    }
}

extern "C" void kernel_launch(void* const* d_in, const int* in_sizes, int n_in,
                              void* d_out, int out_size, void* d_ws, size_t ws_size,
                              hipStream_t stream) {
    const float* z      = (const float*)d_in[0];
    const float* sldj   = (const float*)d_in[1];
    const int*   labels = (const int*)d_in[2];
    const float* beta   = (const float*)d_in[3];
    const float* means  = (const float*)d_in[4];
    float* out = (float*)d_out;

    char* ws = (char*)d_ws;
    size_t off = 0;
    u16* zb = (u16*)(ws + off);      off += (size_t)NB * ND * 2;    // 25.2 MB
    u16* mb = (u16*)(ws + off);      off += (size_t)NCP * ND * 2;   //  6.3 MB
    float* z2 = (float*)(ws + off);  off += (size_t)NB * 4;
    float* m2 = (float*)(ws + off);  off += (size_t)NCP * 4;
    float* cross = (float*)(ws + off); off += (size_t)NB * NCP * 4; // 16.8 MB (slice 0)
    float* ra = (float*)(ws + off);  off += (size_t)NB * 4;
    float* rb = (float*)(ws + off);  off += (size_t)NB * 4;
    const size_t need1 = off;
    off += (size_t)NB * NCP * 4;                                    // 16.8 MB (slice 1)
    const size_t need2 = off;

    const bool split2 = (ws_size >= need2);
    (void)need1;

    convert_all_kernel<<<NB + NCP, 256, 0, stream>>>(z, means, zb, mb, z2, m2);

    if (split2) {
        gemm_dists_kernel<2><<<dim3(NCP / BN, NB / BM, 2), 256, 0, stream>>>(zb, mb, cross);
        row_lse_kernel<2><<<NB, 256, 0, stream>>>(cross, z2, m2, labels, sldj, ra, rb);
    } else {
        gemm_dists_kernel<1><<<dim3(NCP / BN, NB / BM, 1), 256, 0, stream>>>(zb, mb, cross);
        row_lse_kernel<1><<<NB, 256, 0, stream>>>(cross, z2, m2, labels, sldj, ra, rb);
    }
    finalize_kernel<<<1, 1024, 0, stream>>>(ra, rb, beta, out);
}

// Round 6
// 68.444 us; speedup vs baseline: 1.2892x; 1.0061x over previous
//
#include <hip/hip_runtime.h>
#include <hip/hip_bf16.h>
#include <cstdint>
#include <cstddef>

#define NB 4096     // batch rows
#define NC 1000     // real classes
#define NCP 1024    // padded classes
#define ND 3072     // feature dim

typedef __attribute__((ext_vector_type(8))) __bf16 bf16x8;
typedef __attribute__((ext_vector_type(4))) float f32x4;
typedef __attribute__((ext_vector_type(4))) unsigned short u16x4;
typedef unsigned short u16;

__device__ __forceinline__ u16 f2bf_rne(float x) {
    uint32_t u = __float_as_uint(x);
    uint32_t r = (u + 0x7fffu + ((u >> 16) & 1u)) >> 16;
    return (u16)r;
}

// ---------------------------------------------------------------------------
// Fused convert: blocks [0,NB) convert z rows; blocks [NB, NB+NCP) convert
// means rows (rows >= NC zero-padded with sq = 1e30 to kill them in the LSE).
// ---------------------------------------------------------------------------
__global__ __launch_bounds__(256) void convert_all_kernel(
        const float* __restrict__ z, const float* __restrict__ means,
        u16* __restrict__ zb, u16* __restrict__ mb,
        float* __restrict__ z2, float* __restrict__ m2) {
    const int bidx = blockIdx.x;
    const int tid = threadIdx.x;
    const float* src;
    u16* dst;
    float* sq;
    bool pad = false;
    if (bidx < NB) {
        src = z + (size_t)bidx * ND;
        dst = zb + (size_t)bidx * ND;
        sq = z2 + bidx;
    } else {
        const int mr = bidx - NB;
        dst = mb + (size_t)mr * ND;
        sq = m2 + mr;
        src = means + (size_t)mr * ND;
        pad = (mr >= NC);
    }
    if (!pad) {
        const float4* s = (const float4*)src;
        float acc = 0.f;
#pragma unroll
        for (int i = 0; i < 3; ++i) {                // 768 float4 / 256 threads
            const int idx = tid + i * 256;
            float4 v = s[idx];
            acc = fmaf(v.x, v.x, acc);
            acc = fmaf(v.y, v.y, acc);
            acc = fmaf(v.z, v.z, acc);
            acc = fmaf(v.w, v.w, acc);
            u16x4 o;
            o.x = f2bf_rne(v.x); o.y = f2bf_rne(v.y);
            o.z = f2bf_rne(v.z); o.w = f2bf_rne(v.w);
            *(u16x4*)(dst + idx * 4) = o;
        }
#pragma unroll
        for (int off = 32; off > 0; off >>= 1) acc += __shfl_xor(acc, off, 64);
        __shared__ float ssum[4];
        const int wid = tid >> 6, lane = tid & 63;
        if (lane == 0) ssum[wid] = acc;
        __syncthreads();
        if (tid == 0) sq[0] = ssum[0] + ssum[1] + ssum[2] + ssum[3];
    } else {
        u16x4 z4 = (u16x4){0, 0, 0, 0};
#pragma unroll
        for (int i = 0; i < 3; ++i) *(u16x4*)(dst + (tid + i * 256) * 4) = z4;
        if (tid == 0) sq[0] = 1e30f;
    }
}

// ---------------------------------------------------------------------------
// cross_part[ksl][b][c] = sum over K-slice of z_b . mu_c  (raw partial GEMM).
// 128x128 tile, BK=32, 4 waves (2x2, wave tile 64x64, 4x4 acc).
// m97-style loop: 2 LDS buffers (32 KiB -> 4 blocks/CU with launch_bounds(,4)),
// STAGE(t+1) issued before COMP(t), one raw s_barrier + vmcnt(0) per K-step.
// Latency hidden by cross-block TLP (16 waves/CU), not pipeline depth.
// T2 XOR swizzle: physical slot p holds k-slot s = p ^ ((row>>1)&3).
// ---------------------------------------------------------------------------
#define BM 128
#define BN 128
#define BK 32
#define ABUF (BM * BK)          // 4096 elems (8 KiB)
#define BBUF (BN * BK)

#define GLOAD_LDS16(gp, lp)                                            \
    __builtin_amdgcn_global_load_lds(                                  \
        (const __attribute__((address_space(1))) void*)(gp),           \
        (__attribute__((address_space(3))) void*)(lp), 16, 0, 0)

template <int NSL>
__global__ __launch_bounds__(256, 4) void gemm_dists_kernel(
        const u16* __restrict__ zb, const u16* __restrict__ mb,
        float* __restrict__ cross) {
    constexpr int KSL = ND / NSL;        // K elems per slice
    constexpr int NT  = KSL / BK;        // tiles per slice (48 for NSL=2)

    __shared__ u16 As[2 * ABUF];   // 16 KiB (2 buffers)
    __shared__ u16 Bs[2 * BBUF];   // 16 KiB

    const int tid  = threadIdx.x;
    const int wid  = tid >> 6;
    const int lane = tid & 63;
    const int wr   = wid >> 1;        // wave row 0..1 (64 rows each)
    const int wc   = wid & 1;        // wave col 0..1 (64 cols each)
    const int lrow = lane & 15;       // fragment row index
    const int kgrp = lane >> 4;       // k-group 0..3

    // T1: bijective XCD-chunked swizzle within each z-slice (256 % 8 == 0)
    const int bid = blockIdx.y * gridDim.x + blockIdx.x;
    const int swz = (bid & 7) * 32 + (bid >> 3);
    const int brow = (swz >> 3) * BM;     // gridDim.x = 8
    const int bcol = (swz & 7) * BN;
    const int kbase = blockIdx.z * KSL;
    float* outp = cross + (size_t)blockIdx.z * NB * NCP;

    f32x4 acc[4][4];
#pragma unroll
    for (int m = 0; m < 4; ++m)
#pragma unroll
        for (int n = 0; n < 4; ++n) acc[m][n] = (f32x4){0.f, 0.f, 0.f, 0.f};

    // Staging: chunk c (16B) -> physical (row = c>>2, slot p = c&3).
    // Physical slot p holds global k-slot s = p ^ ((row>>1)&3).
    const u16* gA[2]; const u16* gB[2];
    u16* lA[2];       u16* lB[2];
#pragma unroll
    for (int g = 0; g < 2; ++g) {
        const int c = g * 256 + tid;
        const int r = c >> 2, p = c & 3, s = p ^ ((r >> 1) & 3);
        gA[g] = zb + (size_t)(brow + r) * ND + kbase + s * 8;
        gB[g] = mb + (size_t)(bcol + r) * ND + kbase + s * 8;
        lA[g] = As + (g * 256 + wid * 64) * 8;   // wave-uniform base (buf 0)
        lB[g] = Bs + (g * 256 + wid * 64) * 8;
    }

#define STAGE(tt) do {                                                   \
        const int bb_ = (tt) & 1;                                        \
        const int ko_ = (tt) * BK;                                       \
        GLOAD_LDS16(gA[0] + ko_, lA[0] + bb_ * ABUF);                    \
        GLOAD_LDS16(gA[1] + ko_, lA[1] + bb_ * ABUF);                    \
        GLOAD_LDS16(gB[0] + ko_, lB[0] + bb_ * BBUF);                    \
        GLOAD_LDS16(gB[1] + ko_, lB[1] + bb_ * BBUF);                    \
    } while (0)

#define COMP(tt) do {                                                    \
        const int cb_ = (tt) & 1;                                        \
        const u16* Ac = As + cb_ * ABUF;                                 \
        const u16* Bc = Bs + cb_ * BBUF;                                 \
        const int pk = kgrp ^ ((lrow >> 1) & 3);                         \
        bf16x8 a[4], b[4];                                               \
        _Pragma("unroll")                                                \
        for (int m = 0; m < 4; ++m)                                      \
            a[m] = *(const bf16x8*)&Ac[(wr * 64 + m * 16 + lrow) * BK + pk * 8]; \
        _Pragma("unroll")                                                \
        for (int n = 0; n < 4; ++n)                                      \
            b[n] = *(const bf16x8*)&Bc[(wc * 64 + n * 16 + lrow) * BK + pk * 8]; \
        _Pragma("unroll")                                                \
        for (int m = 0; m < 4; ++m)                                      \
            _Pragma("unroll")                                            \
            for (int n = 0; n < 4; ++n)                                  \
                acc[m][n] = __builtin_amdgcn_mfma_f32_16x16x32_bf16(     \
                    a[m], b[n], acc[m][n], 0, 0, 0);                     \
    } while (0)

    // prologue: stage tile 0 into buffer 0
    STAGE(0);

    for (int t = 0; t < NT; ++t) {
        asm volatile("s_waitcnt vmcnt(0)" ::: "memory");  // tile t landed
        __builtin_amdgcn_s_barrier();          // all waves: tile t visible;
                                               // buf (t+1)&1 reads all done
        __builtin_amdgcn_sched_barrier(0);
        if (t + 1 < NT) STAGE(t + 1);          // overlaps with COMP(t) below
        __builtin_amdgcn_sched_barrier(0);     // keep loads issued before reads
        COMP(t);
    }

#undef STAGE
#undef COMP

    // epilogue: C/D layout col = lane&15, row = (lane>>4)*4 + r  (raw cross)
#pragma unroll
    for (int n = 0; n < 4; ++n) {
        const int gcol = bcol + wc * 64 + n * 16 + lrow;
#pragma unroll
        for (int m = 0; m < 4; ++m) {
#pragma unroll
            for (int r = 0; r < 4; ++r) {
                const int grow = brow + wr * 64 + m * 16 + kgrp * 4 + r;
                outp[(size_t)grow * NCP + gcol] = acc[m][n][r];
            }
        }
    }
}

// ---------------------------------------------------------------------------
// Per-row: sum K-slice partials, fold bias (-0.5*(z2+m2)), logsumexp + picked.
// outA[b] = lse - dists[b,label], outB[b] = lse + sldj[b]
// ---------------------------------------------------------------------------
template <int NSL>
__global__ __launch_bounds__(256) void row_lse_kernel(
        const float* __restrict__ cross, const float* __restrict__ z2,
        const float* __restrict__ m2, const int* __restrict__ labels,
        const float* __restrict__ sldj, float* __restrict__ outA,
        float* __restrict__ outB) {
    const int row = blockIdx.x;
    const int tid = threadIdx.x;
    const float* dr0 = cross + (size_t)row * NCP;
    const float* dr1 = cross + (size_t)NB * NCP + (size_t)row * NCP;
    const float z2h = 0.5f * z2[row];
    float4 v = ((const float4*)dr0)[tid];    // 256 * 4 = 1024 exactly
    if (NSL == 2) {
        float4 w = ((const float4*)dr1)[tid];
        v.x += w.x; v.y += w.y; v.z += w.z; v.w += w.w;
    }
    float4 mm = ((const float4*)m2)[tid];
    v.x = v.x - z2h - 0.5f * mm.x;
    v.y = v.y - z2h - 0.5f * mm.y;
    v.z = v.z - z2h - 0.5f * mm.z;
    v.w = v.w - z2h - 0.5f * mm.w;

    float mx = fmaxf(fmaxf(v.x, v.y), fmaxf(v.z, v.w));
#pragma unroll
    for (int off = 32; off > 0; off >>= 1) mx = fmaxf(mx, __shfl_xor(mx, off, 64));
    __shared__ float smax[4], ssum[4];
    const int wid = tid >> 6, lane = tid & 63;
    if (lane == 0) smax[wid] = mx;
    __syncthreads();
    const float bm = fmaxf(fmaxf(smax[0], smax[1]), fmaxf(smax[2], smax[3]));

    float s = expf(v.x - bm) + expf(v.y - bm) + expf(v.z - bm) + expf(v.w - bm);
#pragma unroll
    for (int off = 32; off > 0; off >>= 1) s += __shfl_xor(s, off, 64);
    if (lane == 0) ssum[wid] = s;
    __syncthreads();
    if (tid == 0) {
        const float tot = ssum[0] + ssum[1] + ssum[2] + ssum[3];
        const float lpz = bm + logf(tot);
        const int lab = labels[row];
        float pick = dr0[lab];
        if (NSL == 2) pick += dr1[lab];
        pick = pick - z2h - 0.5f * m2[lab];
        outA[row] = lpz - pick;
        outB[row] = lpz + sldj[row];
    }
}

// ---------------------------------------------------------------------------
// Deterministic final reduction (single block, fixed tree order).
// ---------------------------------------------------------------------------
__global__ __launch_bounds__(1024) void finalize_kernel(
        const float* __restrict__ a, const float* __restrict__ b,
        const float* __restrict__ beta, float* __restrict__ out) {
    __shared__ float sa[1024], sb[1024];
    const int tid = threadIdx.x;
    float va = 0.f, vb = 0.f;
    for (int i = tid; i < NB; i += 1024) { va += a[i]; vb += b[i]; }
    sa[tid] = va; sb[tid] = vb;
    __syncthreads();
    for (int s = 512; s > 0; s >>= 1) {
        if (tid < s) { sa[tid] += sa[tid + s]; sb[tid] += sb[tid + s]; }
        __syncthreads();
    }
    if (tid == 0) {
        const float loss_cls = sa[0] / (float)NB;
        const float loss_gen = -(sb[0] / (float)NB) / (float)ND;
        const float total = loss_gen + beta[0] * loss_cls;
        out[0] = total;
        out[1] = loss_gen;
        out[2] = loss_cls;
    }
}

extern "C" void kernel_launch(void* const* d_in, const int* in_sizes, int n_in,
                              void* d_out, int out_size, void* d_ws, size_t ws_size,
                              hipStream_t stream) {
    const float* z      = (const float*)d_in[0];
    const float* sldj   = (const float*)d_in[1];
    const int*   labels = (const int*)d_in[2];
    const float* beta   = (const float*)d_in[3];
    const float* means  = (const float*)d_in[4];
    float* out = (float*)d_out;

    char* ws = (char*)d_ws;
    size_t off = 0;
    u16* zb = (u16*)(ws + off);      off += (size_t)NB * ND * 2;    // 25.2 MB
    u16* mb = (u16*)(ws + off);      off += (size_t)NCP * ND * 2;   //  6.3 MB
    float* z2 = (float*)(ws + off);  off += (size_t)NB * 4;
    float* m2 = (float*)(ws + off);  off += (size_t)NCP * 4;
    float* cross = (float*)(ws + off); off += (size_t)NB * NCP * 4; // 16.8 MB (slice 0)
    float* ra = (float*)(ws + off);  off += (size_t)NB * 4;
    float* rb = (float*)(ws + off);  off += (size_t)NB * 4;
    const size_t need1 = off;
    off += (size_t)NB * NCP * 4;                                    // 16.8 MB (slice 1)
    const size_t need2 = off;

    const bool split2 = (ws_size >= need2);
    (void)need1;

    convert_all_kernel<<<NB + NCP, 256, 0, stream>>>(z, means, zb, mb, z2, m2);

    if (split2) {
        gemm_dists_kernel<2><<<dim3(NCP / BN, NB / BM, 2), 256, 0, stream>>>(zb, mb, cross);
        row_lse_kernel<2><<<NB, 256, 0, stream>>>(cross, z2, m2, labels, sldj, ra, rb);
    } else {
        gemm_dists_kernel<1><<<dim3(NCP / BN, NB / BM, 1), 256, 0, stream>>>(zb, mb, cross);
        row_lse_kernel<1><<<NB, 256, 0, stream>>>(cross, z2, m2, labels, sldj, ra, rb);
    }
    finalize_kernel<<<1, 1024, 0, stream>>>(ra, rb, beta, out);
}

// Round 8
// 66.993 us; speedup vs baseline: 1.3171x; 1.0217x over previous
//
#include <hip/hip_runtime.h>
#include <hip/hip_bf16.h>
#include <cstdint>
#include <cstddef>

#define NB 4096     // batch rows
#define NC 1000     // real classes
#define NCP 1024    // padded classes
#define ND 3072     // feature dim
#define NSL 4       // split-K slices
#define KSL (ND / NSL)   // 768
#define BM 128
#define BN 128
#define BK 32
#define NT (KSL / BK)    // 24 K-steps per slice
#define ABUF (BM * BK)   // 4096 elems (8 KiB bf16)
#define BBUF (BN * BK)

typedef __attribute__((ext_vector_type(8))) __bf16 bf16x8;
typedef __attribute__((ext_vector_type(4))) float f32x4;
typedef __attribute__((ext_vector_type(4))) unsigned short u16x4;
typedef __attribute__((ext_vector_type(4))) _Float16 f16x4;
typedef unsigned short u16;

__device__ __forceinline__ u16 f2bf_rne(float x) {
    uint32_t u = __float_as_uint(x);
    uint32_t r = (u + 0x7fffu + ((u >> 16) & 1u)) >> 16;
    return (u16)r;
}

// ---------------------------------------------------------------------------
// Convert means f32 -> bf16, + m2 = ||mu||^2.
// Rows >= NC zero-padded with m2 = 1e30 (kills padded classes in the LSE).
// ---------------------------------------------------------------------------
__global__ __launch_bounds__(256) void convert_means_kernel(
        const float* __restrict__ means, u16* __restrict__ mb,
        float* __restrict__ m2) {
    const int row = blockIdx.x;
    const int tid = threadIdx.x;
    u16* dst = mb + (size_t)row * ND;
    if (row < NC) {
        const float4* s = (const float4*)(means + (size_t)row * ND);
        float acc = 0.f;
#pragma unroll
        for (int i = 0; i < 3; ++i) {                // 768 float4 / 256 threads
            const int idx = tid + i * 256;
            float4 v = s[idx];
            acc = fmaf(v.x, v.x, acc);
            acc = fmaf(v.y, v.y, acc);
            acc = fmaf(v.z, v.z, acc);
            acc = fmaf(v.w, v.w, acc);
            u16x4 o;
            o.x = f2bf_rne(v.x); o.y = f2bf_rne(v.y);
            o.z = f2bf_rne(v.z); o.w = f2bf_rne(v.w);
            *(u16x4*)(dst + idx * 4) = o;
        }
#pragma unroll
        for (int off = 32; off > 0; off >>= 1) acc += __shfl_xor(acc, off, 64);
        __shared__ float ssum[4];
        const int wid = tid >> 6, lane = tid & 63;
        if (lane == 0) ssum[wid] = acc;
        __syncthreads();
        if (tid == 0) m2[row] = ssum[0] + ssum[1] + ssum[2] + ssum[3];
    } else {
        u16x4 z4 = (u16x4){0, 0, 0, 0};
#pragma unroll
        for (int i = 0; i < 3; ++i) *(u16x4*)(dst + (tid + i * 256) * 4) = z4;
        if (tid == 0) m2[row] = 1e30f;
    }
}

// ---------------------------------------------------------------------------
// crossh[s][b][c] = (f16) sum over K-slice s of z_b . mu_c.
// A is staged DIRECTLY from f32 z: global f32 -> regs -> cvt bf16 -> swizzled
// ds_write (T14 order: issue loads, COMP, vmcnt(0), write, barrier). B via
// global_load_lds from pre-converted bf16 means with pre-swizzled source.
// bcol==0 blocks also emit deterministic per-row partial sumsq (z2p).
// 1024 blocks (8 bcol x 32 brow x 4 ksl) -> 4 blocks/CU, 16 waves/CU.
// ---------------------------------------------------------------------------
#define GLOAD_LDS16(gp, lp)                                            \
    __builtin_amdgcn_global_load_lds(                                  \
        (const __attribute__((address_space(1))) void*)(gp),           \
        (__attribute__((address_space(3))) void*)(lp), 16, 0, 0)

__global__ __launch_bounds__(256, 4) void gemm_kernel(
        const float* __restrict__ z, const u16* __restrict__ mb,
        _Float16* __restrict__ crossh, float* __restrict__ z2p) {
    __shared__ u16 As[2 * ABUF];   // 16 KiB (2 buffers)
    __shared__ u16 Bs[2 * BBUF];   // 16 KiB

    const int tid  = threadIdx.x;
    const int wid  = tid >> 6;
    const int lane = tid & 63;
    const int wr   = wid >> 1;        // wave row 0..1 (64 rows each)
    const int wc   = wid & 1;         // wave col 0..1 (64 cols each)
    const int lrow = lane & 15;       // fragment row index
    const int kgrp = lane >> 4;       // k-group 0..3

    // XCD-chunked work assignment: XCD x handles work ids [x*128, x*128+128)
    // = one half of a K-slice (A-panels + 1.5 MB B-slice stay XCD-local).
    const int bid = blockIdx.x;
    const int w = (bid & 7) * 128 + (bid >> 3);
    const int bcol8 = w & 7;
    const int brow  = ((w >> 3) & 31) * BM;
    const int ksl   = w >> 8;
    const int bcol  = bcol8 * BN;
    const int kbase = ksl * KSL;
    const bool do_ssq = (bcol8 == 0);

    f32x4 acc[4][4];
#pragma unroll
    for (int m = 0; m < 4; ++m)
#pragma unroll
        for (int n = 0; n < 4; ++n) acc[m][n] = (f32x4){0.f, 0.f, 0.f, 0.f};

    // A reg-stage map: chunk c = g*256+tid -> row r = c>>3, 4-float grp q = c&7.
    // LDS slot s = q>>1 stored at physical p = s ^ ((r>>1)&3), half h = q&1.
    const float* gA[4];
    u16* wAp[4];
#pragma unroll
    for (int g = 0; g < 4; ++g) {
        const int c = g * 256 + tid;
        const int r = c >> 3, q = c & 7;
        const int p = (q >> 1) ^ ((r >> 1) & 3);
        gA[g]  = z + (size_t)(brow + r) * ND + kbase + q * 4;
        wAp[g] = As + r * BK + p * 8 + (q & 1) * 4;
    }
    // B staging: chunk c = g*256+tid -> r = c>>2, phys slot p = c&3,
    // global k-slot s = p ^ ((r>>1)&3)  (XOR involution, DMA-linear dest).
    const u16* gB[2];
    u16* lB[2];
#pragma unroll
    for (int g = 0; g < 2; ++g) {
        const int c = g * 256 + tid;
        const int r = c >> 2, p = c & 3, s = p ^ ((r >> 1) & 3);
        gB[g] = mb + (size_t)(bcol + r) * ND + kbase + s * 8;
        lB[g] = Bs + (g * 256 + wid * 64) * 8;   // wave-uniform base (buf 0)
    }

    float4 areg[4];
    float ssq0 = 0.f, ssq1 = 0.f, ssq2 = 0.f, ssq3 = 0.f;

#define ISSUE(tt, nb_) do {                                              \
        const int ko_ = (tt) * BK;                                       \
        areg[0] = *(const float4*)(gA[0] + ko_);                         \
        areg[1] = *(const float4*)(gA[1] + ko_);                         \
        areg[2] = *(const float4*)(gA[2] + ko_);                         \
        areg[3] = *(const float4*)(gA[3] + ko_);                         \
        GLOAD_LDS16(gB[0] + ko_, lB[0] + (nb_) * BBUF);                  \
        GLOAD_LDS16(gB[1] + ko_, lB[1] + (nb_) * BBUF);                  \
    } while (0)

#define WRITEA(nb_) do {                                                 \
        _Pragma("unroll")                                                \
        for (int g = 0; g < 4; ++g) {                                    \
            u16x4 o;                                                     \
            o.x = f2bf_rne(areg[g].x); o.y = f2bf_rne(areg[g].y);        \
            o.z = f2bf_rne(areg[g].z); o.w = f2bf_rne(areg[g].w);        \
            *(u16x4*)(wAp[g] + (nb_) * ABUF) = o;                        \
        }                                                                \
        if (do_ssq) {                                                    \
            ssq0 = fmaf(areg[0].x, areg[0].x, fmaf(areg[0].y, areg[0].y, \
                   fmaf(areg[0].z, areg[0].z, fmaf(areg[0].w, areg[0].w, ssq0)))); \
            ssq1 = fmaf(areg[1].x, areg[1].x, fmaf(areg[1].y, areg[1].y, \
                   fmaf(areg[1].z, areg[1].z, fmaf(areg[1].w, areg[1].w, ssq1)))); \
            ssq2 = fmaf(areg[2].x, areg[2].x, fmaf(areg[2].y, areg[2].y, \
                   fmaf(areg[2].z, areg[2].z, fmaf(areg[2].w, areg[2].w, ssq2)))); \
            ssq3 = fmaf(areg[3].x, areg[3].x, fmaf(areg[3].y, areg[3].y, \
                   fmaf(areg[3].z, areg[3].z, fmaf(areg[3].w, areg[3].w, ssq3)))); \
        }                                                                \
    } while (0)

// BK=32: one MFMA K-pass per step; logical k-slot kgrp lives at phys slot
// pk = kgrp ^ ((row>>1)&3); row's low bits reduce to lrow (64/16 multiples
// drop out of (row>>1)&3).
#define COMP(tt) do {                                                    \
        const int cb_ = (tt) & 1;                                        \
        const u16* Ac = As + cb_ * ABUF;                                 \
        const u16* Bc = Bs + cb_ * BBUF;                                 \
        const int pk = kgrp ^ ((lrow >> 1) & 3);                         \
        bf16x8 a0 = *(const bf16x8*)&Ac[(wr * 64 +  0 + lrow) * BK + pk * 8]; \
        bf16x8 a1 = *(const bf16x8*)&Ac[(wr * 64 + 16 + lrow) * BK + pk * 8]; \
        bf16x8 a2 = *(const bf16x8*)&Ac[(wr * 64 + 32 + lrow) * BK + pk * 8]; \
        bf16x8 a3 = *(const bf16x8*)&Ac[(wr * 64 + 48 + lrow) * BK + pk * 8]; \
        _Pragma("unroll")                                                \
        for (int n = 0; n < 4; ++n) {                                    \
            bf16x8 bn = *(const bf16x8*)&Bc[(wc * 64 + n * 16 + lrow) * BK + pk * 8]; \
            acc[0][n] = __builtin_amdgcn_mfma_f32_16x16x32_bf16(a0, bn, acc[0][n], 0, 0, 0); \
            acc[1][n] = __builtin_amdgcn_mfma_f32_16x16x32_bf16(a1, bn, acc[1][n], 0, 0, 0); \
            acc[2][n] = __builtin_amdgcn_mfma_f32_16x16x32_bf16(a2, bn, acc[2][n], 0, 0, 0); \
            acc[3][n] = __builtin_amdgcn_mfma_f32_16x16x32_bf16(a3, bn, acc[3][n], 0, 0, 0); \
        }                                                                \
    } while (0)

    // prologue: stage tile 0 into buffer 0
    ISSUE(0, 0);
    asm volatile("s_waitcnt vmcnt(0)" ::: "memory");
    WRITEA(0);
    asm volatile("s_waitcnt lgkmcnt(0)" ::: "memory");
    __builtin_amdgcn_s_barrier();
    __builtin_amdgcn_sched_barrier(0);

    for (int t = 0; t < NT; ++t) {
        const int nxt = (t + 1) & 1;
        if (t + 1 < NT) ISSUE(t + 1, nxt);     // loads in flight over COMP
        __builtin_amdgcn_sched_barrier(0);
        COMP(t);
        if (t + 1 < NT) {
            asm volatile("s_waitcnt vmcnt(0)" ::: "memory");  // A regs + B DMA landed
            WRITEA(nxt);
        }
        asm volatile("s_waitcnt lgkmcnt(0)" ::: "memory");    // ds_writes visible
        __builtin_amdgcn_s_barrier();
        __builtin_amdgcn_sched_barrier(0);
    }

#undef ISSUE
#undef WRITEA
#undef COMP

    // deterministic per-row partial sumsq (only bcol==0 blocks; no atomics)
    if (do_ssq) {
        float* sb = (float*)As;      // reuse LDS (barrier above guarantees free)
        sb[0 * 256 + tid] = ssq0;
        sb[1 * 256 + tid] = ssq1;
        sb[2 * 256 + tid] = ssq2;
        sb[3 * 256 + tid] = ssq3;
        __syncthreads();
        if (tid < BM) {
            const int g = tid >> 5;
            const int base = (tid * 8) & 255;
            float s = 0.f;
#pragma unroll
            for (int j = 0; j < 8; ++j) s += sb[g * 256 + base + j];
            z2p[(size_t)ksl * NB + brow + tid] = s;
        }
    }

    // epilogue: C/D layout col = lane&15, row = (lane>>4)*4 + r  (f16 partial)
    _Float16* outp = crossh + (size_t)ksl * NB * NCP;
#pragma unroll
    for (int n = 0; n < 4; ++n) {
        const int gcol = bcol + wc * 64 + n * 16 + lrow;
#pragma unroll
        for (int m = 0; m < 4; ++m) {
#pragma unroll
            for (int r = 0; r < 4; ++r) {
                const int grow = brow + wr * 64 + m * 16 + kgrp * 4 + r;
                outp[(size_t)grow * NCP + gcol] = (_Float16)acc[m][n][r];
            }
        }
    }
}

// ---------------------------------------------------------------------------
// Per-row: d'[c] = sum_s crossh[s][b][c] - 0.5*m2[c]  (z^2 cancels in loss_cls;
// its grand mean is applied in finalize). outA = LSE'(d') - d'[label],
// outB = LSE'(d') + sldj[b].
// ---------------------------------------------------------------------------
__global__ __launch_bounds__(256) void row_lse_kernel(
        const _Float16* __restrict__ crossh, const float* __restrict__ m2,
        const int* __restrict__ labels, const float* __restrict__ sldj,
        float* __restrict__ outA, float* __restrict__ outB) {
    const int row = blockIdx.x;
    const int tid = threadIdx.x;

    float a0 = 0.f, a1 = 0.f, a2 = 0.f, a3 = 0.f;
#pragma unroll
    for (int s = 0; s < NSL; ++s) {
        f16x4 h = ((const f16x4*)(crossh + ((size_t)s * NB + row) * NCP))[tid];
        a0 += (float)h.x; a1 += (float)h.y; a2 += (float)h.z; a3 += (float)h.w;
    }
    float4 mm = ((const float4*)m2)[tid];
    float4 v;
    v.x = a0 - 0.5f * mm.x;
    v.y = a1 - 0.5f * mm.y;
    v.z = a2 - 0.5f * mm.z;
    v.w = a3 - 0.5f * mm.w;

    float mx = fmaxf(fmaxf(v.x, v.y), fmaxf(v.z, v.w));
#pragma unroll
    for (int off = 32; off > 0; off >>= 1) mx = fmaxf(mx, __shfl_xor(mx, off, 64));
    __shared__ float smax[4], ssum[4];
    const int wid = tid >> 6, lane = tid & 63;
    if (lane == 0) smax[wid] = mx;
    __syncthreads();
    const float bm = fmaxf(fmaxf(smax[0], smax[1]), fmaxf(smax[2], smax[3]));

    float s = expf(v.x - bm) + expf(v.y - bm) + expf(v.z - bm) + expf(v.w - bm);
#pragma unroll
    for (int off = 32; off > 0; off >>= 1) s += __shfl_xor(s, off, 64);
    if (lane == 0) ssum[wid] = s;
    __syncthreads();
    if (tid == 0) {
        const float tot = ssum[0] + ssum[1] + ssum[2] + ssum[3];
        const float lpz = bm + logf(tot);
        const int lab = labels[row];
        float pick = 0.f;
#pragma unroll
        for (int si = 0; si < NSL; ++si)
            pick += (float)crossh[((size_t)si * NB + row) * NCP + lab];
        pick -= 0.5f * m2[lab];
        outA[row] = lpz - pick;
        outB[row] = lpz + sldj[row];
    }
}

// ---------------------------------------------------------------------------
// Deterministic final reduction. loss_cls = mean(outA);
// mean(log_pz + sldj) = mean(outB) - 0.5*mean(z2);  loss_gen = -that/ND.
// ---------------------------------------------------------------------------
__global__ __launch_bounds__(1024) void finalize_kernel(
        const float* __restrict__ a, const float* __restrict__ b,
        const float* __restrict__ z2p, const float* __restrict__ beta,
        float* __restrict__ out) {
    __shared__ float sa[1024], sb[1024], sz[1024];
    const int tid = threadIdx.x;
    float va = 0.f, vb = 0.f, vz = 0.f;
    for (int i = tid; i < NB; i += 1024) { va += a[i]; vb += b[i]; }
    for (int i = tid; i < NSL * NB; i += 1024) vz += z2p[i];
    sa[tid] = va; sb[tid] = vb; sz[tid] = vz;
    __syncthreads();
    for (int s = 512; s > 0; s >>= 1) {
        if (tid < s) {
            sa[tid] += sa[tid + s];
            sb[tid] += sb[tid + s];
            sz[tid] += sz[tid + s];
        }
        __syncthreads();
    }
    if (tid == 0) {
        const float loss_cls = sa[0] / (float)NB;
        const float mean_lpz_sldj = sb[0] / (float)NB - 0.5f * (sz[0] / (float)NB);
        const float loss_gen = -mean_lpz_sldj / (float)ND;
        const float total = loss_gen + beta[0] * loss_cls;
        out[0] = total;
        out[1] = loss_gen;
        out[2] = loss_cls;
    }
}

extern "C" void kernel_launch(void* const* d_in, const int* in_sizes, int n_in,
                              void* d_out, int out_size, void* d_ws, size_t ws_size,
                              hipStream_t stream) {
    const float* z      = (const float*)d_in[0];
    const float* sldj   = (const float*)d_in[1];
    const int*   labels = (const int*)d_in[2];
    const float* beta   = (const float*)d_in[3];
    const float* means  = (const float*)d_in[4];
    float* out = (float*)d_out;

    char* ws = (char*)d_ws;
    size_t off = 0;
    u16* mb = (u16*)(ws + off);           off += (size_t)NCP * ND * 2;        //  6.3 MB
    float* m2 = (float*)(ws + off);       off += (size_t)NCP * 4;
    _Float16* crossh = (_Float16*)(ws + off); off += (size_t)NSL * NB * NCP * 2; // 33.6 MB
    float* z2p = (float*)(ws + off);      off += (size_t)NSL * NB * 4;
    float* ra = (float*)(ws + off);       off += (size_t)NB * 4;
    float* rb = (float*)(ws + off);       off += (size_t)NB * 4;

    convert_means_kernel<<<NCP, 256, 0, stream>>>(means, mb, m2);
    gemm_kernel<<<8 * 32 * NSL, 256, 0, stream>>>(z, mb, crossh, z2p);
    row_lse_kernel<<<NB, 256, 0, stream>>>(crossh, m2, labels, sldj, ra, rb);
    finalize_kernel<<<1, 1024, 0, stream>>>(ra, rb, z2p, beta, out);
}

// Round 9
// 66.067 us; speedup vs baseline: 1.3356x; 1.0140x over previous
//
#include <hip/hip_runtime.h>
#include <hip/hip_bf16.h>
#include <cstdint>
#include <cstddef>

#define NB 4096     // batch rows
#define NC 1000     // real classes
#define NCP 1024    // padded classes
#define ND 3072     // feature dim
#define NSL 4       // split-K slices
#define KSL (ND / NSL)   // 768
#define BM 128
#define BN 128
#define BK 32
#define NT (KSL / BK)    // 24 K-steps per slice
#define ABUF (BM * BK)   // 4096 elems (8 KiB bf16)
#define BBUF (BN * BK)

typedef __attribute__((ext_vector_type(8))) __bf16 bf16x8;
typedef __attribute__((ext_vector_type(4))) float f32x4;
typedef __attribute__((ext_vector_type(4))) unsigned short u16x4;
typedef __attribute__((ext_vector_type(4))) _Float16 f16x4;
typedef unsigned short u16;

__device__ __forceinline__ u16 f2bf_rne(float x) {
    uint32_t u = __float_as_uint(x);
    uint32_t r = (u + 0x7fffu + ((u >> 16) & 1u)) >> 16;
    return (u16)r;
}

// ---------------------------------------------------------------------------
// Fused convert: blocks [0,NB) convert z rows (z2 = ||z||^2); blocks
// [NB, NB+NCP) convert means rows (rows >= NC zero-padded, m2 = 1e30 kills
// padded classes in the LSE).
// ---------------------------------------------------------------------------
__global__ __launch_bounds__(256) void convert_all_kernel(
        const float* __restrict__ z, const float* __restrict__ means,
        u16* __restrict__ zb, u16* __restrict__ mb,
        float* __restrict__ z2, float* __restrict__ m2) {
    const int bidx = blockIdx.x;
    const int tid = threadIdx.x;
    const float* src;
    u16* dst;
    float* sq;
    bool pad = false;
    if (bidx < NB) {
        src = z + (size_t)bidx * ND;
        dst = zb + (size_t)bidx * ND;
        sq = z2 + bidx;
    } else {
        const int mr = bidx - NB;
        dst = mb + (size_t)mr * ND;
        sq = m2 + mr;
        src = means + (size_t)mr * ND;
        pad = (mr >= NC);
    }
    if (!pad) {
        const float4* s = (const float4*)src;
        float acc = 0.f;
#pragma unroll
        for (int i = 0; i < 3; ++i) {                // 768 float4 / 256 threads
            const int idx = tid + i * 256;
            float4 v = s[idx];
            acc = fmaf(v.x, v.x, acc);
            acc = fmaf(v.y, v.y, acc);
            acc = fmaf(v.z, v.z, acc);
            acc = fmaf(v.w, v.w, acc);
            u16x4 o;
            o.x = f2bf_rne(v.x); o.y = f2bf_rne(v.y);
            o.z = f2bf_rne(v.z); o.w = f2bf_rne(v.w);
            *(u16x4*)(dst + idx * 4) = o;
        }
#pragma unroll
        for (int off = 32; off > 0; off >>= 1) acc += __shfl_xor(acc, off, 64);
        __shared__ float ssum[4];
        const int wid = tid >> 6, lane = tid & 63;
        if (lane == 0) ssum[wid] = acc;
        __syncthreads();
        if (tid == 0) sq[0] = ssum[0] + ssum[1] + ssum[2] + ssum[3];
    } else {
        u16x4 z4 = (u16x4){0, 0, 0, 0};
#pragma unroll
        for (int i = 0; i < 3; ++i) *(u16x4*)(dst + (tid + i * 256) * 4) = z4;
        if (tid == 0) sq[0] = 1e30f;
    }
}

// ---------------------------------------------------------------------------
// crossh[s][b][c] = (f16) sum over K-slice s of z_b . mu_c  (raw partials).
// R6-verified structure: 128x128 tile, BK=32, 4 waves (2x2, wave tile 64x64),
// 2 LDS buffers (32 KiB), global_load_lds both operands, one raw s_barrier +
// vmcnt(0) per K-step. NSL=4 -> grid 1024 = 4 blocks/CU (16 waves/CU): the
// per-block barrier drain is hidden by the other 3 blocks' compute.
// T2 XOR swizzle: physical slot p holds k-slot s = p ^ ((row>>1)&3).
// ---------------------------------------------------------------------------
#define GLOAD_LDS16(gp, lp)                                            \
    __builtin_amdgcn_global_load_lds(                                  \
        (const __attribute__((address_space(1))) void*)(gp),           \
        (__attribute__((address_space(3))) void*)(lp), 16, 0, 0)

__global__ __launch_bounds__(256, 4) void gemm_kernel(
        const u16* __restrict__ zb, const u16* __restrict__ mb,
        _Float16* __restrict__ crossh) {
    __shared__ u16 As[2 * ABUF];   // 16 KiB (2 buffers)
    __shared__ u16 Bs[2 * BBUF];   // 16 KiB

    const int tid  = threadIdx.x;
    const int wid  = tid >> 6;
    const int lane = tid & 63;
    const int wr   = wid >> 1;        // wave row 0..1 (64 rows each)
    const int wc   = wid & 1;         // wave col 0..1 (64 cols each)
    const int lrow = lane & 15;       // fragment row index
    const int kgrp = lane >> 4;       // k-group 0..3

    // XCD-chunked work assignment: the 8 blocks sharing an A-panel are
    // consecutive w within one XCD chunk -> A-panel stays L2-local.
    const int bid = blockIdx.x;
    const int w = (bid & 7) * 128 + (bid >> 3);
    const int bcol8 = w & 7;
    const int brow  = ((w >> 3) & 31) * BM;
    const int ksl   = w >> 8;
    const int bcol  = bcol8 * BN;
    const int kbase = ksl * KSL;

    f32x4 acc[4][4];
#pragma unroll
    for (int m = 0; m < 4; ++m)
#pragma unroll
        for (int n = 0; n < 4; ++n) acc[m][n] = (f32x4){0.f, 0.f, 0.f, 0.f};

    // Staging: chunk c (16B) -> physical (row = c>>2, slot p = c&3).
    // Physical slot p holds global k-slot s = p ^ ((r>>1)&3) (XOR involution,
    // DMA-linear dest; verified 0 bank conflicts in R6).
    const u16* gA[2]; const u16* gB[2];
    u16* lA[2];       u16* lB[2];
#pragma unroll
    for (int g = 0; g < 2; ++g) {
        const int c = g * 256 + tid;
        const int r = c >> 2, p = c & 3, s = p ^ ((r >> 1) & 3);
        gA[g] = zb + (size_t)(brow + r) * ND + kbase + s * 8;
        gB[g] = mb + (size_t)(bcol + r) * ND + kbase + s * 8;
        lA[g] = As + (g * 256 + wid * 64) * 8;   // wave-uniform base (buf 0)
        lB[g] = Bs + (g * 256 + wid * 64) * 8;
    }

#define STAGE(tt) do {                                                   \
        const int bb_ = (tt) & 1;                                        \
        const int ko_ = (tt) * BK;                                       \
        GLOAD_LDS16(gA[0] + ko_, lA[0] + bb_ * ABUF);                    \
        GLOAD_LDS16(gA[1] + ko_, lA[1] + bb_ * ABUF);                    \
        GLOAD_LDS16(gB[0] + ko_, lB[0] + bb_ * BBUF);                    \
        GLOAD_LDS16(gB[1] + ko_, lB[1] + bb_ * BBUF);                    \
    } while (0)

#define COMP(tt) do {                                                    \
        const int cb_ = (tt) & 1;                                        \
        const u16* Ac = As + cb_ * ABUF;                                 \
        const u16* Bc = Bs + cb_ * BBUF;                                 \
        const int pk = kgrp ^ ((lrow >> 1) & 3);                         \
        bf16x8 a0 = *(const bf16x8*)&Ac[(wr * 64 +  0 + lrow) * BK + pk * 8]; \
        bf16x8 a1 = *(const bf16x8*)&Ac[(wr * 64 + 16 + lrow) * BK + pk * 8]; \
        bf16x8 a2 = *(const bf16x8*)&Ac[(wr * 64 + 32 + lrow) * BK + pk * 8]; \
        bf16x8 a3 = *(const bf16x8*)&Ac[(wr * 64 + 48 + lrow) * BK + pk * 8]; \
        _Pragma("unroll")                                                \
        for (int n = 0; n < 4; ++n) {                                    \
            bf16x8 bn = *(const bf16x8*)&Bc[(wc * 64 + n * 16 + lrow) * BK + pk * 8]; \
            acc[0][n] = __builtin_amdgcn_mfma_f32_16x16x32_bf16(a0, bn, acc[0][n], 0, 0, 0); \
            acc[1][n] = __builtin_amdgcn_mfma_f32_16x16x32_bf16(a1, bn, acc[1][n], 0, 0, 0); \
            acc[2][n] = __builtin_amdgcn_mfma_f32_16x16x32_bf16(a2, bn, acc[2][n], 0, 0, 0); \
            acc[3][n] = __builtin_amdgcn_mfma_f32_16x16x32_bf16(a3, bn, acc[3][n], 0, 0, 0); \
        }                                                                \
    } while (0)

    // prologue: stage tile 0 into buffer 0
    STAGE(0);

    for (int t = 0; t < NT; ++t) {
        asm volatile("s_waitcnt vmcnt(0)" ::: "memory");  // tile t landed
        __builtin_amdgcn_s_barrier();          // all waves: tile t visible;
                                               // buf (t+1)&1 reads all done
        __builtin_amdgcn_sched_barrier(0);
        if (t + 1 < NT) STAGE(t + 1);          // overlaps with COMP(t) below
        __builtin_amdgcn_sched_barrier(0);     // keep loads issued before reads
        COMP(t);
    }

#undef STAGE
#undef COMP

    // epilogue: C/D layout col = lane&15, row = (lane>>4)*4 + r  (f16 partial)
    _Float16* outp = crossh + (size_t)ksl * NB * NCP;
#pragma unroll
    for (int n = 0; n < 4; ++n) {
        const int gcol = bcol + wc * 64 + n * 16 + lrow;
#pragma unroll
        for (int m = 0; m < 4; ++m) {
#pragma unroll
            for (int r = 0; r < 4; ++r) {
                const int grow = brow + wr * 64 + m * 16 + kgrp * 4 + r;
                outp[(size_t)grow * NCP + gcol] = (_Float16)acc[m][n][r];
            }
        }
    }
}

// ---------------------------------------------------------------------------
// Per-row: d'[c] = sum_s crossh[s][b][c] - 0.5*m2[c].  z^2 cancels exactly in
// loss_cls (outA = LSE(d') - d'[label]); its mean is applied in finalize for
// loss_gen.  outB = LSE(d') + sldj[b].
// ---------------------------------------------------------------------------
__global__ __launch_bounds__(256) void row_lse_kernel(
        const _Float16* __restrict__ crossh, const float* __restrict__ m2,
        const int* __restrict__ labels, const float* __restrict__ sldj,
        float* __restrict__ outA, float* __restrict__ outB) {
    const int row = blockIdx.x;
    const int tid = threadIdx.x;

    float a0 = 0.f, a1 = 0.f, a2 = 0.f, a3 = 0.f;
#pragma unroll
    for (int s = 0; s < NSL; ++s) {
        f16x4 h = ((const f16x4*)(crossh + ((size_t)s * NB + row) * NCP))[tid];
        a0 += (float)h.x; a1 += (float)h.y; a2 += (float)h.z; a3 += (float)h.w;
    }
    float4 mm = ((const float4*)m2)[tid];
    float4 v;
    v.x = a0 - 0.5f * mm.x;
    v.y = a1 - 0.5f * mm.y;
    v.z = a2 - 0.5f * mm.z;
    v.w = a3 - 0.5f * mm.w;

    float mx = fmaxf(fmaxf(v.x, v.y), fmaxf(v.z, v.w));
#pragma unroll
    for (int off = 32; off > 0; off >>= 1) mx = fmaxf(mx, __shfl_xor(mx, off, 64));
    __shared__ float smax[4], ssum[4];
    const int wid = tid >> 6, lane = tid & 63;
    if (lane == 0) smax[wid] = mx;
    __syncthreads();
    const float bm = fmaxf(fmaxf(smax[0], smax[1]), fmaxf(smax[2], smax[3]));

    float s = expf(v.x - bm) + expf(v.y - bm) + expf(v.z - bm) + expf(v.w - bm);
#pragma unroll
    for (int off = 32; off > 0; off >>= 1) s += __shfl_xor(s, off, 64);
    if (lane == 0) ssum[wid] = s;
    __syncthreads();
    if (tid == 0) {
        const float tot = ssum[0] + ssum[1] + ssum[2] + ssum[3];
        const float lpz = bm + logf(tot);
        const int lab = labels[row];
        float pick = 0.f;
#pragma unroll
        for (int si = 0; si < NSL; ++si)
            pick += (float)crossh[((size_t)si * NB + row) * NCP + lab];
        pick -= 0.5f * m2[lab];
        outA[row] = lpz - pick;
        outB[row] = lpz + sldj[row];
    }
}

// ---------------------------------------------------------------------------
// Deterministic final reduction. loss_cls = mean(outA);
// mean(log_pz + sldj) = mean(outB) - 0.5*mean(z2);  loss_gen = -that/ND.
// ---------------------------------------------------------------------------
__global__ __launch_bounds__(1024) void finalize_kernel(
        const float* __restrict__ a, const float* __restrict__ b,
        const float* __restrict__ z2, const float* __restrict__ beta,
        float* __restrict__ out) {
    __shared__ float sa[1024], sb[1024], sz[1024];
    const int tid = threadIdx.x;
    float va = 0.f, vb = 0.f, vz = 0.f;
    for (int i = tid; i < NB; i += 1024) {
        va += a[i]; vb += b[i]; vz += z2[i];
    }
    sa[tid] = va; sb[tid] = vb; sz[tid] = vz;
    __syncthreads();
    for (int s = 512; s > 0; s >>= 1) {
        if (tid < s) {
            sa[tid] += sa[tid + s];
            sb[tid] += sb[tid + s];
            sz[tid] += sz[tid + s];
        }
        __syncthreads();
    }
    if (tid == 0) {
        const float loss_cls = sa[0] / (float)NB;
        const float mean_lpz_sldj = sb[0] / (float)NB - 0.5f * (sz[0] / (float)NB);
        const float loss_gen = -mean_lpz_sldj / (float)ND;
        const float total = loss_gen + beta[0] * loss_cls;
        out[0] = total;
        out[1] = loss_gen;
        out[2] = loss_cls;
    }
}

extern "C" void kernel_launch(void* const* d_in, const int* in_sizes, int n_in,
                              void* d_out, int out_size, void* d_ws, size_t ws_size,
                              hipStream_t stream) {
    const float* z      = (const float*)d_in[0];
    const float* sldj   = (const float*)d_in[1];
    const int*   labels = (const int*)d_in[2];
    const float* beta   = (const float*)d_in[3];
    const float* means  = (const float*)d_in[4];
    float* out = (float*)d_out;

    char* ws = (char*)d_ws;
    size_t off = 0;
    u16* zb = (u16*)(ws + off);           off += (size_t)NB * ND * 2;          // 25.2 MB
    u16* mb = (u16*)(ws + off);           off += (size_t)NCP * ND * 2;         //  6.3 MB
    float* z2 = (float*)(ws + off);       off += (size_t)NB * 4;
    float* m2 = (float*)(ws + off);       off += (size_t)NCP * 4;
    _Float16* crossh = (_Float16*)(ws + off); off += (size_t)NSL * NB * NCP * 2; // 33.6 MB
    float* ra = (float*)(ws + off);       off += (size_t)NB * 4;
    float* rb = (float*)(ws + off);       off += (size_t)NB * 4;

    convert_all_kernel<<<NB + NCP, 256, 0, stream>>>(z, means, zb, mb, z2, m2);
    gemm_kernel<<<8 * 32 * NSL, 256, 0, stream>>>(zb, mb, crossh);
    row_lse_kernel<<<NB, 256, 0, stream>>>(crossh, m2, labels, sldj, ra, rb);
    finalize_kernel<<<1, 1024, 0, stream>>>(ra, rb, z2, beta, out);
}

// Round 10
// 60.437 us; speedup vs baseline: 1.4600x; 1.0932x over previous
//
#include <hip/hip_runtime.h>
#include <hip/hip_bf16.h>
#include <cstdint>
#include <cstddef>

#define NB 4096     // batch rows
#define NC 1000     // real classes
#define NCP 1024    // padded classes
#define ND 3072     // feature dim
#define NSL 4       // split-K slices
#define KSL (ND / NSL)   // 768
#define BM 256
#define BN 256
#define BK 32
#define NT (KSL / BK)    // 24 K-steps per slice
#define ABUF (BM * BK)   // 8192 elems (16 KiB bf16)
#define BBUF (BN * BK)

typedef __attribute__((ext_vector_type(8))) __bf16 bf16x8;
typedef __attribute__((ext_vector_type(4))) float f32x4;
typedef __attribute__((ext_vector_type(4))) unsigned short u16x4;
typedef __attribute__((ext_vector_type(4))) _Float16 f16x4;
typedef unsigned short u16;

__device__ __forceinline__ u16 f2bf_rne(float x) {
    uint32_t u = __float_as_uint(x);
    uint32_t r = (u + 0x7fffu + ((u >> 16) & 1u)) >> 16;
    return (u16)r;
}

// ---------------------------------------------------------------------------
// Fused convert: blocks [0,NB) convert z rows (z2 = ||z||^2); blocks
// [NB, NB+NCP) convert means rows (rows >= NC zero-padded, m2 = 1e30 kills
// padded classes in the LSE).
// ---------------------------------------------------------------------------
__global__ __launch_bounds__(256) void convert_all_kernel(
        const float* __restrict__ z, const float* __restrict__ means,
        u16* __restrict__ zb, u16* __restrict__ mb,
        float* __restrict__ z2, float* __restrict__ m2) {
    const int bidx = blockIdx.x;
    const int tid = threadIdx.x;
    const float* src;
    u16* dst;
    float* sq;
    bool pad = false;
    if (bidx < NB) {
        src = z + (size_t)bidx * ND;
        dst = zb + (size_t)bidx * ND;
        sq = z2 + bidx;
    } else {
        const int mr = bidx - NB;
        dst = mb + (size_t)mr * ND;
        sq = m2 + mr;
        src = means + (size_t)mr * ND;
        pad = (mr >= NC);
    }
    if (!pad) {
        const float4* s = (const float4*)src;
        float acc = 0.f;
#pragma unroll
        for (int i = 0; i < 3; ++i) {                // 768 float4 / 256 threads
            const int idx = tid + i * 256;
            float4 v = s[idx];
            acc = fmaf(v.x, v.x, acc);
            acc = fmaf(v.y, v.y, acc);
            acc = fmaf(v.z, v.z, acc);
            acc = fmaf(v.w, v.w, acc);
            u16x4 o;
            o.x = f2bf_rne(v.x); o.y = f2bf_rne(v.y);
            o.z = f2bf_rne(v.z); o.w = f2bf_rne(v.w);
            *(u16x4*)(dst + idx * 4) = o;
        }
#pragma unroll
        for (int off = 32; off > 0; off >>= 1) acc += __shfl_xor(acc, off, 64);
        __shared__ float ssum[4];
        const int wid = tid >> 6, lane = tid & 63;
        if (lane == 0) ssum[wid] = acc;
        __syncthreads();
        if (tid == 0) sq[0] = ssum[0] + ssum[1] + ssum[2] + ssum[3];
    } else {
        u16x4 z4 = (u16x4){0, 0, 0, 0};
#pragma unroll
        for (int i = 0; i < 3; ++i) *(u16x4*)(dst + (tid + i * 256) * 4) = z4;
        if (tid == 0) sq[0] = 1e30f;
    }
}

// ---------------------------------------------------------------------------
// crossh[s][b][c] = (f16) sum over K-slice s of z_b . mu_c  (raw partials).
// 256x256 tile (quarters staged bytes: 201 MB total vs 402 at 128x128),
// 16 waves (1024 thr, 4x4 wave grid, each wave the VERIFIED 64x64 sub-tile),
// BK=32, 4 LDS buffers (128 KiB), depth-3 counted-vmcnt pipeline (R4/R5-
// verified; 2 loads/thread/stage -> vmcnt 4/2/0), one raw s_barrier/step.
// In-block TLP = 4 waves/SIMD hides DMA latency. NSL=4 -> grid 256.
// T2 XOR swizzle: physical slot p holds k-slot s = p ^ ((row>>1)&3).
// ---------------------------------------------------------------------------
#define GLOAD_LDS16(gp, lp)                                            \
    __builtin_amdgcn_global_load_lds(                                  \
        (const __attribute__((address_space(1))) void*)(gp),           \
        (__attribute__((address_space(3))) void*)(lp), 16, 0, 0)

__global__ __launch_bounds__(1024, 4) void gemm_kernel(
        const u16* __restrict__ zb, const u16* __restrict__ mb,
        _Float16* __restrict__ crossh) {
    __shared__ u16 As[4 * ABUF];   // 64 KiB (4 buffers)
    __shared__ u16 Bs[4 * BBUF];   // 64 KiB

    const int tid  = threadIdx.x;
    const int wid  = tid >> 6;
    const int lane = tid & 63;
    const int wrr  = (wid >> 2) * 64;    // wave row offset (0..192)
    const int wcc  = (wid & 3) * 64;     // wave col offset (0..192)
    const int lrow = lane & 15;          // fragment row index
    const int kgrp = lane >> 4;          // k-group 0..3

    // XCD-chunked work: 32 consecutive w per XCD (half a K-slice: 8 brows x
    // 4 bcols share panels within one XCD's L2).
    const int bid = blockIdx.x;
    const int w = (bid & 7) * 32 + (bid >> 3);
    const int ksl  = w >> 6;
    const int rem  = w & 63;
    const int brow = (rem >> 2) * BM;
    const int bcol = (rem & 3) * BN;
    const int kbase = ksl * KSL;

    f32x4 acc[4][4];
#pragma unroll
    for (int m = 0; m < 4; ++m)
#pragma unroll
        for (int n = 0; n < 4; ++n) acc[m][n] = (f32x4){0.f, 0.f, 0.f, 0.f};

    // Staging: chunk c = tid (16B) -> row r = c>>2, phys slot p = c&3.
    // Physical slot p holds global k-slot s = p ^ ((r>>1)&3) (XOR involution,
    // DMA-linear dest; verified 0 bank conflicts in R6/R9).
    const u16* gA;
    const u16* gB;
    u16* lA;
    u16* lB;
    {
        const int r = tid >> 2, p = tid & 3, s = p ^ ((r >> 1) & 3);
        gA = zb + (size_t)(brow + r) * ND + kbase + s * 8;
        gB = mb + (size_t)(bcol + r) * ND + kbase + s * 8;
        lA = As + wid * 512;     // wave-uniform base (buf 0): 64 chunks/wave
        lB = Bs + wid * 512;
    }

#define STAGE(tt) do {                                                   \
        const int bb_ = (tt) & 3;                                        \
        const int ko_ = (tt) * BK;                                       \
        GLOAD_LDS16(gA + ko_, lA + bb_ * ABUF);                          \
        GLOAD_LDS16(gB + ko_, lB + bb_ * BBUF);                          \
    } while (0)

#define COMP(tt) do {                                                    \
        const int cb_ = (tt) & 3;                                        \
        const u16* Ac = As + cb_ * ABUF;                                 \
        const u16* Bc = Bs + cb_ * BBUF;                                 \
        const int pk = kgrp ^ ((lrow >> 1) & 3);                         \
        bf16x8 a0 = *(const bf16x8*)&Ac[(wrr +  0 + lrow) * BK + pk * 8]; \
        bf16x8 a1 = *(const bf16x8*)&Ac[(wrr + 16 + lrow) * BK + pk * 8]; \
        bf16x8 a2 = *(const bf16x8*)&Ac[(wrr + 32 + lrow) * BK + pk * 8]; \
        bf16x8 a3 = *(const bf16x8*)&Ac[(wrr + 48 + lrow) * BK + pk * 8]; \
        _Pragma("unroll")                                                \
        for (int n = 0; n < 4; ++n) {                                    \
            bf16x8 bn = *(const bf16x8*)&Bc[(wcc + n * 16 + lrow) * BK + pk * 8]; \
            acc[0][n] = __builtin_amdgcn_mfma_f32_16x16x32_bf16(a0, bn, acc[0][n], 0, 0, 0); \
            acc[1][n] = __builtin_amdgcn_mfma_f32_16x16x32_bf16(a1, bn, acc[1][n], 0, 0, 0); \
            acc[2][n] = __builtin_amdgcn_mfma_f32_16x16x32_bf16(a2, bn, acc[2][n], 0, 0, 0); \
            acc[3][n] = __builtin_amdgcn_mfma_f32_16x16x32_bf16(a3, bn, acc[3][n], 0, 0, 0); \
        }                                                                \
    } while (0)

    // prologue: stage tiles 0,1,2 into buffers 0,1,2 (6 loads/thread in flight)
    STAGE(0); STAGE(1); STAGE(2);

    // main loop: counted vmcnt — tiles t+1, t+2 stay in flight across barrier
    for (int t = 0; t < NT - 2; ++t) {
        asm volatile("s_waitcnt vmcnt(4)" ::: "memory");   // tile t landed
        __builtin_amdgcn_s_barrier();      // tile t visible; buf (t+3)&3 free
        __builtin_amdgcn_sched_barrier(0);
        if (t + 3 < NT) STAGE(t + 3);
        __builtin_amdgcn_sched_barrier(0);
        COMP(t);
    }
    // tail: t = NT-2, NT-1
    asm volatile("s_waitcnt vmcnt(2)" ::: "memory");
    __builtin_amdgcn_s_barrier();
    __builtin_amdgcn_sched_barrier(0);
    COMP(NT - 2);
    asm volatile("s_waitcnt vmcnt(0)" ::: "memory");
    __builtin_amdgcn_s_barrier();
    __builtin_amdgcn_sched_barrier(0);
    COMP(NT - 1);

#undef STAGE
#undef COMP

    // epilogue: C/D layout col = lane&15, row = (lane>>4)*4 + r  (f16 partial)
    _Float16* outp = crossh + (size_t)ksl * NB * NCP;
#pragma unroll
    for (int n = 0; n < 4; ++n) {
        const int gcol = bcol + wcc + n * 16 + lrow;
#pragma unroll
        for (int m = 0; m < 4; ++m) {
#pragma unroll
            for (int r = 0; r < 4; ++r) {
                const int grow = brow + wrr + m * 16 + kgrp * 4 + r;
                outp[(size_t)grow * NCP + gcol] = (_Float16)acc[m][n][r];
            }
        }
    }
}

// ---------------------------------------------------------------------------
// Per-row: d'[c] = sum_s crossh[s][b][c] - 0.5*m2[c].  z^2 cancels exactly in
// loss_cls (outA = LSE(d') - d'[label]); its mean is applied in finalize for
// loss_gen.  outB = LSE(d') + sldj[b].
// ---------------------------------------------------------------------------
__global__ __launch_bounds__(256) void row_lse_kernel(
        const _Float16* __restrict__ crossh, const float* __restrict__ m2,
        const int* __restrict__ labels, const float* __restrict__ sldj,
        float* __restrict__ outA, float* __restrict__ outB) {
    const int row = blockIdx.x;
    const int tid = threadIdx.x;

    float a0 = 0.f, a1 = 0.f, a2 = 0.f, a3 = 0.f;
#pragma unroll
    for (int s = 0; s < NSL; ++s) {
        f16x4 h = ((const f16x4*)(crossh + ((size_t)s * NB + row) * NCP))[tid];
        a0 += (float)h.x; a1 += (float)h.y; a2 += (float)h.z; a3 += (float)h.w;
    }
    float4 mm = ((const float4*)m2)[tid];
    float4 v;
    v.x = a0 - 0.5f * mm.x;
    v.y = a1 - 0.5f * mm.y;
    v.z = a2 - 0.5f * mm.z;
    v.w = a3 - 0.5f * mm.w;

    float mx = fmaxf(fmaxf(v.x, v.y), fmaxf(v.z, v.w));
#pragma unroll
    for (int off = 32; off > 0; off >>= 1) mx = fmaxf(mx, __shfl_xor(mx, off, 64));
    __shared__ float smax[4], ssum[4];
    const int wid = tid >> 6, lane = tid & 63;
    if (lane == 0) smax[wid] = mx;
    __syncthreads();
    const float bm = fmaxf(fmaxf(smax[0], smax[1]), fmaxf(smax[2], smax[3]));

    float s = expf(v.x - bm) + expf(v.y - bm) + expf(v.z - bm) + expf(v.w - bm);
#pragma unroll
    for (int off = 32; off > 0; off >>= 1) s += __shfl_xor(s, off, 64);
    if (lane == 0) ssum[wid] = s;
    __syncthreads();
    if (tid == 0) {
        const float tot = ssum[0] + ssum[1] + ssum[2] + ssum[3];
        const float lpz = bm + logf(tot);
        const int lab = labels[row];
        float pick = 0.f;
#pragma unroll
        for (int si = 0; si < NSL; ++si)
            pick += (float)crossh[((size_t)si * NB + row) * NCP + lab];
        pick -= 0.5f * m2[lab];
        outA[row] = lpz - pick;
        outB[row] = lpz + sldj[row];
    }
}

// ---------------------------------------------------------------------------
// Deterministic final reduction. loss_cls = mean(outA);
// mean(log_pz + sldj) = mean(outB) - 0.5*mean(z2);  loss_gen = -that/ND.
// ---------------------------------------------------------------------------
__global__ __launch_bounds__(1024) void finalize_kernel(
        const float* __restrict__ a, const float* __restrict__ b,
        const float* __restrict__ z2, const float* __restrict__ beta,
        float* __restrict__ out) {
    __shared__ float sa[1024], sb[1024], sz[1024];
    const int tid = threadIdx.x;
    float va = 0.f, vb = 0.f, vz = 0.f;
    for (int i = tid; i < NB; i += 1024) {
        va += a[i]; vb += b[i]; vz += z2[i];
    }
    sa[tid] = va; sb[tid] = vb; sz[tid] = vz;
    __syncthreads();
    for (int s = 512; s > 0; s >>= 1) {
        if (tid < s) {
            sa[tid] += sa[tid + s];
            sb[tid] += sb[tid + s];
            sz[tid] += sz[tid + s];
        }
        __syncthreads();
    }
    if (tid == 0) {
        const float loss_cls = sa[0] / (float)NB;
        const float mean_lpz_sldj = sb[0] / (float)NB - 0.5f * (sz[0] / (float)NB);
        const float loss_gen = -mean_lpz_sldj / (float)ND;
        const float total = loss_gen + beta[0] * loss_cls;
        out[0] = total;
        out[1] = loss_gen;
        out[2] = loss_cls;
    }
}

extern "C" void kernel_launch(void* const* d_in, const int* in_sizes, int n_in,
                              void* d_out, int out_size, void* d_ws, size_t ws_size,
                              hipStream_t stream) {
    const float* z      = (const float*)d_in[0];
    const float* sldj   = (const float*)d_in[1];
    const int*   labels = (const int*)d_in[2];
    const float* beta   = (const float*)d_in[3];
    const float* means  = (const float*)d_in[4];
    float* out = (float*)d_out;

    char* ws = (char*)d_ws;
    size_t off = 0;
    u16* zb = (u16*)(ws + off);           off += (size_t)NB * ND * 2;          // 25.2 MB
    u16* mb = (u16*)(ws + off);           off += (size_t)NCP * ND * 2;         //  6.3 MB
    float* z2 = (float*)(ws + off);       off += (size_t)NB * 4;
    float* m2 = (float*)(ws + off);       off += (size_t)NCP * 4;
    _Float16* crossh = (_Float16*)(ws + off); off += (size_t)NSL * NB * NCP * 2; // 33.6 MB
    float* ra = (float*)(ws + off);       off += (size_t)NB * 4;
    float* rb = (float*)(ws + off);       off += (size_t)NB * 4;

    convert_all_kernel<<<NB + NCP, 256, 0, stream>>>(z, means, zb, mb, z2, m2);
    gemm_kernel<<<8 * 32 * NSL / 4, 1024, 0, stream>>>(zb, mb, crossh);
    row_lse_kernel<<<NB, 256, 0, stream>>>(crossh, m2, labels, sldj, ra, rb);
    finalize_kernel<<<1, 1024, 0, stream>>>(ra, rb, z2, beta, out);
}